// Round 20
// baseline (211.009 us; speedup 1.0000x reference)
//
#include <hip/hip_runtime.h>
#include <cstdint>
#include <cstddef>

#define B_ 2
#define T_ 2048
#define D_ 1024
#define H_ 16
#define HD_ 64
#define NC_ 32

typedef unsigned short u16;
typedef __attribute__((ext_vector_type(8))) short bf16x8;
typedef __attribute__((ext_vector_type(4))) float f32x4;

__device__ __forceinline__ float dot4(float4 a, float4 b, float acc) {
  return fmaf(a.x, b.x, fmaf(a.y, b.y, fmaf(a.z, b.z, fmaf(a.w, b.w, acc))));
}
__device__ __forceinline__ u16 f2bf(float f) {
  unsigned u = __float_as_uint(f);
  u += 0x7fffu + ((u >> 16) & 1u);
  return (u16)(u >> 16);
}
__device__ __forceinline__ float bf2f(u16 v) {
  return __uint_as_float(((unsigned)v) << 16);
}
__device__ __forceinline__ float4 ld4bf(const u16* p) {
  uint2 v = *(const uint2*)p;
  return float4{__uint_as_float(v.x << 16),
                __uint_as_float(v.x & 0xffff0000u),
                __uint_as_float(v.y << 16),
                __uint_as_float(v.y & 0xffff0000u)};
}
__device__ __forceinline__ bf16x8 pack8(float4 a, float4 b) {
  union { u16 us[8]; bf16x8 v; } p;
  p.us[0] = f2bf(a.x); p.us[1] = f2bf(a.y); p.us[2] = f2bf(a.z); p.us[3] = f2bf(a.w);
  p.us[4] = f2bf(b.x); p.us[5] = f2bf(b.y); p.us[6] = f2bf(b.z); p.us[7] = f2bf(b.w);
  return p.v;
}
__device__ __forceinline__ void glds16(const u16* g, u16* l) {
  __builtin_amdgcn_global_load_lds(
      (const __attribute__((address_space(1))) void*)g,
      (__attribute__((address_space(3))) void*)l, 16, 0, 0);
}
// causal conv (K=4) on 4 columns; w[cc] = taps for column cc
__device__ __forceinline__ float4 conv4(float4 x0, float4 x1, float4 x2, float4 x3,
                                        const float4* w) {
  float4 y;
  y.x = fmaf(w[0].x, x0.x, fmaf(w[0].y, x1.x, fmaf(w[0].z, x2.x, w[0].w * x3.x)));
  y.y = fmaf(w[1].x, x0.y, fmaf(w[1].y, x1.y, fmaf(w[1].z, x2.y, w[1].w * x3.y)));
  y.z = fmaf(w[2].x, x0.z, fmaf(w[2].y, x1.z, fmaf(w[2].z, x2.z, w[2].w * x3.z)));
  y.w = fmaf(w[3].x, x0.w, fmaf(w[3].y, x1.w, fmaf(w[3].z, x2.w, w[3].w * x3.w)));
  return y;
}
__device__ __forceinline__ float4 silu4(float4 a) {
  return float4{a.x / (1.f + __expf(-a.x)), a.y / (1.f + __expf(-a.y)),
                a.z / (1.f + __expf(-a.z)), a.w / (1.f + __expf(-a.w))};
}

// ---------------- fp32 -> bf16 conversion (h + 5 weights, one launch) ----------------
__global__ __launch_bounds__(256) void cvt_all(
    const float* __restrict__ h, const float* __restrict__ w0,
    const float* __restrict__ w1, const float* __restrict__ w2,
    const float* __restrict__ w3, const float* __restrict__ w4,
    u16* __restrict__ h_bf, u16* __restrict__ wb)
{
  const int blk = blockIdx.x;
  const float* src;
  u16* dst;
  int lb;
  if (blk < 2048) { src = h; dst = h_bf; lb = blk; }
  else {
    int k = (blk - 2048) >> 9, r = (blk - 2048) & 511;
    src = k == 0 ? w0 : k == 1 ? w1 : k == 2 ? w2 : k == 3 ? w3 : w4;
    dst = wb + (size_t)k * 1048576;
    lb = r;
  }
  int i = (lb * 256 + threadIdx.x) * 8;
  float4 v0 = *(const float4*)(src + i);
  float4 v1 = *(const float4*)(src + i + 4);
  union { u16 us[8]; uint4 u4; } p;
  p.us[0] = f2bf(v0.x); p.us[1] = f2bf(v0.y); p.us[2] = f2bf(v0.z); p.us[3] = f2bf(v0.w);
  p.us[4] = f2bf(v1.x); p.us[5] = f2bf(v1.y); p.us[6] = f2bf(v1.z); p.us[7] = f2bf(v1.w);
  *(uint4*)(dst + i) = p.u4;
}

// ---- 256x256 GEMM (bf16 out): 8 waves x (128x64), BK=64, 4-phase/tile, counted vmcnt ----
__global__ __launch_bounds__(512, 1) void gemm_bf16_4(const u16* __restrict__ A,
    const u16* __restrict__ W0, const u16* __restrict__ W1,
    const u16* __restrict__ W2, const u16* __restrict__ W3,
    u16* __restrict__ C0, u16* __restrict__ C1,
    u16* __restrict__ C2, u16* __restrict__ C3)
{
  __shared__ u16 L[2 * 32768];   // 128 KB
  const int K = 1024, N = 1024, KT = 16;   // BK = 64
  const int sel = blockIdx.y >> 2;
  const u16* Bw = sel == 0 ? W0 : sel == 1 ? W1 : sel == 2 ? W2 : W3;
  u16* C = sel == 0 ? C0 : sel == 1 ? C1 : sel == 2 ? C2 : C3;
  const int row0 = blockIdx.x * 256;
  const int col0 = (blockIdx.y & 3) * 256;
  const int tid = threadIdx.x;
  const int lane = tid & 63, wave = tid >> 6;
  const int wm = wave >> 2, wn = wave & 3;
  const int lr = lane & 15, lkq = lane >> 4;
  const int rr = tid >> 2, cl = tid & 3;
  const int csw = (cl ^ ((rr >> 1) & 3)) * 8;

  f32x4 acc[8][4];
  #pragma unroll
  for (int i = 0; i < 8; ++i)
    #pragma unroll
    for (int j = 0; j < 4; ++j) acc[i][j] = f32x4{0.f, 0.f, 0.f, 0.f};

  auto STAGEU = [&](int buf, int kt, const u16* src, int matOfs, int baseRow, int ks, int rh) {
    glds16(src + (size_t)(baseRow + rh * 128 + rr) * K + kt * 64 + ks * 32 + csw,
           L + buf * 32768 + matOfs + ks * 8192 + rh * 4096 + tid * 8);
  };
  auto rdA = [&](int buf, int ks, int ih, bf16x8* af) {
    #pragma unroll
    for (int i = 0; i < 4; ++i) {
      const int R = wm * 128 + (ih * 4 + i) * 16 + lr;
      af[i] = *(const bf16x8*)&L[buf * 32768 + ks * 8192 + R * 32 + ((lkq ^ ((R >> 1) & 3)) * 8)];
    }
  };
  auto rdB = [&](int buf, int ks, bf16x8* bf) {
    #pragma unroll
    for (int j = 0; j < 4; ++j) {
      const int R = wn * 64 + j * 16 + lr;
      bf[j] = *(const bf16x8*)&L[buf * 32768 + 16384 + ks * 8192 + R * 32 + ((lkq ^ ((R >> 1) & 3)) * 8)];
    }
  };

  STAGEU(0, 0, A, 0, row0, 0, 0);  STAGEU(0, 0, A, 0, row0, 0, 1);
  STAGEU(0, 0, Bw, 16384, col0, 0, 0); STAGEU(0, 0, Bw, 16384, col0, 0, 1);
  STAGEU(0, 0, A, 0, row0, 1, 0);  STAGEU(0, 0, A, 0, row0, 1, 1);
  STAGEU(0, 0, Bw, 16384, col0, 1, 0); STAGEU(0, 0, Bw, 16384, col0, 1, 1);
  asm volatile("s_waitcnt vmcnt(4)" ::: "memory");
  __builtin_amdgcn_s_barrier();
  __builtin_amdgcn_sched_barrier(0);

  for (int kt = 0; kt < KT; ++kt) {
    const int cb = kt & 1, nb = cb ^ 1;
    const bool st = (kt + 1 < KT);
    bf16x8 af[4], bfr[4];
    rdB(cb, 0, bfr);
    rdA(cb, 0, 0, af);
    if (st) { STAGEU(nb, kt + 1, A, 0, row0, 0, 0); STAGEU(nb, kt + 1, A, 0, row0, 0, 1); }
    __builtin_amdgcn_s_barrier();
    asm volatile("s_waitcnt lgkmcnt(0)" ::: "memory");
    __builtin_amdgcn_sched_barrier(0);
    __builtin_amdgcn_s_setprio(1);
    #pragma unroll
    for (int i = 0; i < 4; ++i)
      #pragma unroll
      for (int j = 0; j < 4; ++j)
        acc[i][j] = __builtin_amdgcn_mfma_f32_16x16x32_bf16(af[i], bfr[j], acc[i][j], 0, 0, 0);
    __builtin_amdgcn_s_setprio(0);
    __builtin_amdgcn_sched_barrier(0);
    __builtin_amdgcn_s_barrier();
    rdA(cb, 0, 1, af);
    if (st) { STAGEU(nb, kt + 1, Bw, 16384, col0, 0, 0); STAGEU(nb, kt + 1, Bw, 16384, col0, 0, 1); }
    if (kt == KT - 1) {
      asm volatile("s_waitcnt vmcnt(0)" ::: "memory");
    } else {
      asm volatile("s_waitcnt vmcnt(4)" ::: "memory");
    }
    __builtin_amdgcn_s_barrier();
    asm volatile("s_waitcnt lgkmcnt(0)" ::: "memory");
    __builtin_amdgcn_sched_barrier(0);
    __builtin_amdgcn_s_setprio(1);
    #pragma unroll
    for (int i = 0; i < 4; ++i)
      #pragma unroll
      for (int j = 0; j < 4; ++j)
        acc[4 + i][j] = __builtin_amdgcn_mfma_f32_16x16x32_bf16(af[i], bfr[j], acc[4 + i][j], 0, 0, 0);
    __builtin_amdgcn_s_setprio(0);
    __builtin_amdgcn_sched_barrier(0);
    __builtin_amdgcn_s_barrier();
    rdB(cb, 1, bfr);
    rdA(cb, 1, 0, af);
    if (st) { STAGEU(nb, kt + 1, A, 0, row0, 1, 0); STAGEU(nb, kt + 1, A, 0, row0, 1, 1); }
    __builtin_amdgcn_s_barrier();
    asm volatile("s_waitcnt lgkmcnt(0)" ::: "memory");
    __builtin_amdgcn_sched_barrier(0);
    __builtin_amdgcn_s_setprio(1);
    #pragma unroll
    for (int i = 0; i < 4; ++i)
      #pragma unroll
      for (int j = 0; j < 4; ++j)
        acc[i][j] = __builtin_amdgcn_mfma_f32_16x16x32_bf16(af[i], bfr[j], acc[i][j], 0, 0, 0);
    __builtin_amdgcn_s_setprio(0);
    __builtin_amdgcn_sched_barrier(0);
    __builtin_amdgcn_s_barrier();
    rdA(cb, 1, 1, af);
    if (st) {
      STAGEU(nb, kt + 1, Bw, 16384, col0, 1, 0); STAGEU(nb, kt + 1, Bw, 16384, col0, 1, 1);
      asm volatile("s_waitcnt vmcnt(4)" ::: "memory");
    }
    __builtin_amdgcn_s_barrier();
    asm volatile("s_waitcnt lgkmcnt(0)" ::: "memory");
    __builtin_amdgcn_sched_barrier(0);
    __builtin_amdgcn_s_setprio(1);
    #pragma unroll
    for (int i = 0; i < 4; ++i)
      #pragma unroll
      for (int j = 0; j < 4; ++j)
        acc[4 + i][j] = __builtin_amdgcn_mfma_f32_16x16x32_bf16(af[i], bfr[j], acc[4 + i][j], 0, 0, 0);
    __builtin_amdgcn_s_setprio(0);
    __builtin_amdgcn_sched_barrier(0);
    __builtin_amdgcn_s_barrier();
  }

  const int orow = row0 + wm * 128 + (lane >> 4) * 4;
  const int ocol = col0 + wn * 64 + lr;
  #pragma unroll
  for (int i = 0; i < 8; ++i)
    #pragma unroll
    for (int j = 0; j < 4; ++j)
      #pragma unroll
      for (int r = 0; r < 4; ++r)
        C[(size_t)(orow + i * 16 + r) * N + ocol + j * 16] = f2bf(acc[i][j][r]);
}

// ---------------- 128x128 GEMM core (fp32 output): 4 waves x (64x64), 3-deep pipeline ----------------
__device__ __forceinline__ void gemm_core128(const u16* __restrict__ A,
    const u16* __restrict__ Bw, float* __restrict__ C,
    u16* As, u16* Bs, int row0, int col0, int K, int N)
{
  const int tid = threadIdx.x;
  const int lane = tid & 63, wave = tid >> 6;
  const int wr = (wave >> 1) * 64, wc = (wave & 1) * 64;
  const int lr = lane & 15;
  const int lkp = (((lane >> 4) ^ ((lr >> 1) & 3))) * 8;
  const int rql = (lane >> 2);
  const int cql = (((lane & 3) ^ ((rql >> 1) & 3))) * 8;
  const u16* gA0 = A + (size_t)(row0 + wave * 16 + rql) * K + cql;
  const u16* gA1 = A + (size_t)(row0 + (wave + 4) * 16 + rql) * K + cql;
  const u16* gB0 = Bw + (size_t)(col0 + wave * 16 + rql) * K + cql;
  const u16* gB1 = Bw + (size_t)(col0 + (wave + 4) * 16 + rql) * K + cql;

  f32x4 acc[4][4];
  #pragma unroll
  for (int i = 0; i < 4; ++i)
    #pragma unroll
    for (int j = 0; j < 4; ++j) acc[i][j] = f32x4{0.f, 0.f, 0.f, 0.f};

  auto STAGE = [&](int buf, int kt) {
    u16* ab = As + buf * 4096;
    u16* bb = Bs + buf * 4096;
    glds16(gA0 + kt * 32, ab + wave * 512);
    glds16(gA1 + kt * 32, ab + (wave + 4) * 512);
    glds16(gB0 + kt * 32, bb + wave * 512);
    glds16(gB1 + kt * 32, bb + (wave + 4) * 512);
  };

  const int KT = K >> 5;
  STAGE(0, 0);
  STAGE(1, 1);
  int cur = 0;
  for (int kt = 0; kt < KT; ++kt) {
    if (kt + 2 < KT) {
      STAGE(cur == 0 ? 2 : (cur == 1 ? 0 : 1), kt + 2);
      asm volatile("s_waitcnt vmcnt(8)" ::: "memory");
    } else if (kt + 1 < KT) {
      asm volatile("s_waitcnt vmcnt(4)" ::: "memory");
    } else {
      asm volatile("s_waitcnt vmcnt(0)" ::: "memory");
    }
    __builtin_amdgcn_s_barrier();
    __builtin_amdgcn_sched_barrier(0);
    const u16* Asc = As + cur * 4096;
    const u16* Bsc = Bs + cur * 4096;
    bf16x8 af[4], bf[4];
    #pragma unroll
    for (int i = 0; i < 4; ++i) af[i] = *(const bf16x8*)&Asc[(wr + i * 16 + lr) * 32 + lkp];
    #pragma unroll
    for (int j = 0; j < 4; ++j) bf[j] = *(const bf16x8*)&Bsc[(wc + j * 16 + lr) * 32 + lkp];
    #pragma unroll
    for (int i = 0; i < 4; ++i)
      #pragma unroll
      for (int j = 0; j < 4; ++j)
        acc[i][j] = __builtin_amdgcn_mfma_f32_16x16x32_bf16(af[i], bf[j], acc[i][j], 0, 0, 0);
    __builtin_amdgcn_sched_barrier(0);
    __builtin_amdgcn_s_barrier();
    cur = (cur == 2) ? 0 : cur + 1;
  }
  const int orow = row0 + wr + (lane >> 4) * 4;
  const int ocol = col0 + wc + lr;
  #pragma unroll
  for (int i = 0; i < 4; ++i)
    #pragma unroll
    for (int j = 0; j < 4; ++j)
      #pragma unroll
      for (int r = 0; r < 4; ++r)
        C[(size_t)(orow + i * 16 + r) * N + ocol + j * 16] = acc[i][j][r];
}

__global__ __launch_bounds__(256) void gemm_bf16_1(const u16* __restrict__ A,
    const u16* __restrict__ Bw, float* __restrict__ C)
{
  __shared__ u16 As[3 * 128 * 32];
  __shared__ u16 Bs[3 * 128 * 32];
  gemm_core128(A, Bw, C, As, Bs, blockIdx.x * 128, blockIdx.y * 128, 1024, 1024);
}

// ---------------- smallproj (LDS-tiled fp32): C[4096][32] = h @ [Wa;Wb]^T ----------------
#define SPW 261
__global__ __launch_bounds__(256) void smallproj(const float* __restrict__ Hs,
    const float* __restrict__ Wa, const float* __restrict__ Wb,
    const float* __restrict__ Alog, const float* __restrict__ dtb,
    float* __restrict__ Gout, float* __restrict__ Bout)
{
  __shared__ float hT[16][SPW];
  __shared__ float wT[32][SPW];
  const int row0 = blockIdx.x * 16;
  const int tid = threadIdx.x;
  const int r = tid >> 5;
  const int c = tid & 31;
  float a0 = 0.f, a1 = 0.f;
  for (int kc = 0; kc < 4; ++kc) {
    const int k0 = kc * 256;
    #pragma unroll
    for (int i = 0; i < 4; ++i) {
      int e4 = tid + i * 256;
      int rr = e4 >> 6, k4 = (e4 & 63) * 4;
      *(float4*)&hT[rr][k4] = *(const float4*)&Hs[(size_t)(row0 + rr) * D_ + k0 + k4];
    }
    #pragma unroll
    for (int i = 0; i < 8; ++i) {
      int e4 = tid + i * 256;
      int rr = e4 >> 6, k4 = (e4 & 63) * 4;
      const float* wsrc = (rr < 16) ? (Wa + (size_t)rr * D_) : (Wb + (size_t)(rr - 16) * D_);
      *(float4*)&wT[rr][k4] = *(const float4*)&wsrc[k0 + k4];
    }
    __syncthreads();
    #pragma unroll 8
    for (int k = 0; k < 256; k += 4) {
      float4 wv = *(const float4*)&wT[c][k];
      float4 h0 = *(const float4*)&hT[r][k];
      float4 h1 = *(const float4*)&hT[r + 8][k];
      a0 = dot4(h0, wv, a0);
      a1 = dot4(h1, wv, a1);
    }
    __syncthreads();
  }
  if (c < 16) {
    const float al = -__expf(Alog[c]);
    const float db = dtb[c];
    float x0 = a0 + db, x1 = a1 + db;
    float sp0 = fmaxf(x0, 0.f) + log1pf(__expf(-fabsf(x0)));
    float sp1 = fmaxf(x1, 0.f) + log1pf(__expf(-fabsf(x1)));
    Gout[(size_t)(row0 + r) * H_ + c] = al * sp0;
    Gout[(size_t)(row0 + r + 8) * H_ + c] = al * sp1;
  } else {
    const int hd = c - 16;
    Bout[(size_t)(row0 + r) * H_ + hd] = 1.f / (1.f + __expf(-a0));
    Bout[(size_t)(row0 + r + 8) * H_ + hd] = 1.f / (1.f + __expf(-a1));
  }
}

// ---------------- P1 (fused): conv+SiLU+norm of K, conv+SiLU of V inline (bf16 sources);
//                 A (bf16 LDS) = scale(K K^T), blocked MFMA solve -> U,W (bf16),
//                 then M = bC*I - K^T(sc*W), N = K^T(sc*U) ----------------
__global__ __launch_bounds__(256) void p1_chunk(
    const u16* __restrict__ Kp, const u16* __restrict__ Vp,
    const float* __restrict__ Gg, const float* __restrict__ Bb,
    const float* __restrict__ ckw, const float* __restrict__ cvw,
    const float* __restrict__ knw,
    u16* __restrict__ Ubf, u16* __restrict__ Wbf, u16* __restrict__ Kcb,
    float* __restrict__ Gcum, float* __restrict__ Mbuf, float* __restrict__ Nbuf)
{
  __shared__ u16 Kbf[64][72];
  __shared__ u16 Amb[64][72];      // bf16 A (9216B; was fp32 17.4KB) -> 3 blocks/CU
  __shared__ float XT[128][68];
  __shared__ float gc[64], bet[64], ekt[64];
  const int bhc = blockIdx.x;
  const int bh = bhc >> 5, c = bhc & 31;
  const int b = bh >> 4, h = bh & 15;
  const int tid = threadIdx.x;
  const int lane = tid & 63, wave = tid >> 6;
  const int lr = lane & 15, lkq = lane >> 4;
  const size_t rowbase = ((size_t)b*T_ + c*64)*H_ + h;
  const int c4 = (tid & 15) * 4;
  const int hh64 = h * 64;

  if (tid < 64) {
    float gv = Gg[rowbase + (size_t)tid*H_];
    #pragma unroll
    for (int off = 1; off < 64; off <<= 1) {
      float up = __shfl_up(gv, off, 64);
      if (tid >= off) gv += up;
    }
    gc[tid] = gv;
    Gcum[(size_t)bhc*64 + tid] = gv;
    float bv = Bb[rowbase + (size_t)tid*H_];
    bet[tid] = bv;
    ekt[tid] = bv * __expf(gv);
  }

  // ---- K staging: conv(K=4)+SiLU+RMSNorm+L2Norm -> bf16 LDS + Kcb global ----
  {
    float4 wk[4];
    float nwv[4];
    #pragma unroll
    for (int cc = 0; cc < 4; ++cc) {
      wk[cc] = *(const float4*)(ckw + (hh64 + c4 + cc) * 4);
      nwv[cc] = knw[c4 + cc];
    }
    #pragma unroll
    for (int k = 0; k < 4; ++k) {
      const int t = (tid >> 4) + k * 16;
      const int gt = c * 64 + t;
      const u16* src = Kp + (rowbase + (size_t)t * H_) * 64 + c4;
      float4 x3 = ld4bf(src);
      float4 x2 = (gt >= 1) ? ld4bf(src - D_)   : float4{0,0,0,0};
      float4 x1 = (gt >= 2) ? ld4bf(src - 2*D_) : float4{0,0,0,0};
      float4 x0 = (gt >= 3) ? ld4bf(src - 3*D_) : float4{0,0,0,0};
      float4 y = silu4(conv4(x0, x1, x2, x3, wk));
      float ss = fmaf(y.x, y.x, fmaf(y.y, y.y, fmaf(y.z, y.z, y.w * y.w)));
      ss += __shfl_xor(ss, 1); ss += __shfl_xor(ss, 2);
      ss += __shfl_xor(ss, 4); ss += __shfl_xor(ss, 8);
      const float inv1 = rsqrtf(ss * (1.f/64.f) + 1e-6f);
      float4 z = {y.x*inv1*nwv[0], y.y*inv1*nwv[1], y.z*inv1*nwv[2], y.w*inv1*nwv[3]};
      float s2 = fmaf(z.x, z.x, fmaf(z.y, z.y, fmaf(z.z, z.z, z.w * z.w)));
      s2 += __shfl_xor(s2, 1); s2 += __shfl_xor(s2, 2);
      s2 += __shfl_xor(s2, 4); s2 += __shfl_xor(s2, 8);
      const float inv2 = rsqrtf(s2 + 1e-6f);
      u16 tmp[4] = {f2bf(z.x*inv2), f2bf(z.y*inv2), f2bf(z.z*inv2), f2bf(z.w*inv2)};
      *(uint2*)&Kbf[t][c4] = *(uint2*)tmp;
      *(uint2*)&Kcb[(size_t)bhc*4096 + (size_t)t*64 + c4] = *(uint2*)tmp;
    }
  }
  __syncthreads();

  // ---- A-phase: wave w computes t-strip [16w,16w+16) x all s (bf16 store) ----
  {
    bf16x8 afA[2];
    #pragma unroll
    for (int ks = 0; ks < 2; ++ks)
      afA[ks] = *(const bf16x8*)&Kbf[16*wave + lr][ks*32 + lkq*8];
    __builtin_amdgcn_s_setprio(1);
    #pragma unroll
    for (int j = 0; j < 4; ++j) {
      f32x4 accA = f32x4{0.f, 0.f, 0.f, 0.f};
      #pragma unroll
      for (int ks = 0; ks < 2; ++ks) {
        bf16x8 bfr = *(const bf16x8*)&Kbf[16*j + lr][ks*32 + lkq*8];
        accA = __builtin_amdgcn_mfma_f32_16x16x32_bf16(afA[ks], bfr, accA, 0, 0, 0);
      }
      const int s = 16*j + lr;
      #pragma unroll
      for (int r = 0; r < 4; ++r) {
        int t = 16*wave + lkq*4 + r;
        Amb[t][s] = (s < t) ? f2bf(bet[t] * __expf(gc[t] - gc[s]) * accA[r]) : (u16)0;
      }
    }
    __builtin_amdgcn_s_setprio(0);
  }
  // ---- RHS fill: V conv+SiLU, col-per-lane mapping (conflict-free float4 XT writes) ----
  {
    const int ccol = tid & 63;
    const int tq = tid >> 6;             // t range [16tq, 16tq+16)
    const float4 wv = *(const float4*)(cvw + (hh64 + ccol) * 4);
    float xv[19];
    #pragma unroll
    for (int i = 0; i < 19; ++i) {
      const int t = 16*tq - 3 + i;
      const int gt = c * 64 + t;
      xv[i] = (gt >= 0)
            ? bf2f(Vp[(long long)rowbase * 64 + (long long)t * (H_*64) + ccol])
            : 0.f;
    }
    float o1[16], o2[16];
    #pragma unroll
    for (int i = 0; i < 16; ++i) {
      const int t = 16*tq + i;
      float a = fmaf(wv.x, xv[i], fmaf(wv.y, xv[i+1], fmaf(wv.z, xv[i+2], wv.w * xv[i+3])));
      float y = a / (1.f + __expf(-a));
      o1[i] = bet[t] * y;
      o2[i] = ekt[t] * bf2f(Kbf[t][ccol]);
    }
    #pragma unroll
    for (int q = 0; q < 4; ++q) {
      *(float4*)&XT[ccol][16*tq + q*4]      = *(float4*)&o1[q*4];
      *(float4*)&XT[64 + ccol][16*tq + q*4] = *(float4*)&o2[q*4];
    }
  }
  __syncthreads();

  // ---- blocked forward substitution: 4 stages of 16 rows ----
  for (int st = 0; st < 4; ++st) {
    if (st > 0) {
      const int nks = (st == 3) ? 2 : 1;
      f32x4 accU0 = f32x4{0.f,0.f,0.f,0.f}, accU1 = f32x4{0.f,0.f,0.f,0.f};
      __builtin_amdgcn_s_setprio(1);
      for (int ks = 0; ks < nks; ++ks) {
        const int m0 = ks*32 + lkq*8;
        bf16x8 af;
        if (m0 + 8 <= 16*st) {
          af = *(const bf16x8*)&Amb[16*st + lr][m0];
        } else {
          af = bf16x8{0,0,0,0,0,0,0,0};
        }
        {
          const int cb = (wave*2 + 0) * 16;
          float4 b0 = *(const float4*)&XT[cb + lr][m0];
          float4 b1 = *(const float4*)&XT[cb + lr][m0 + 4];
          accU0 = __builtin_amdgcn_mfma_f32_16x16x32_bf16(af, pack8(b0, b1), accU0, 0, 0, 0);
        }
        {
          const int cb = (wave*2 + 1) * 16;
          float4 b0 = *(const float4*)&XT[cb + lr][m0];
          float4 b1 = *(const float4*)&XT[cb + lr][m0 + 4];
          accU1 = __builtin_amdgcn_mfma_f32_16x16x32_bf16(af, pack8(b0, b1), accU1, 0, 0, 0);
        }
      }
      __builtin_amdgcn_s_setprio(0);
      #pragma unroll
      for (int r = 0; r < 4; ++r) {
        const int t = 16*st + lkq*4 + r;
        XT[(wave*2+0)*16 + lr][t] -= accU0[r];
        XT[(wave*2+1)*16 + lr][t] -= accU1[r];
      }
      __syncthreads();
    }
    if (tid < 128) {
      const int bs = 16*st;
      float x[16];
      #pragma unroll
      for (int q = 0; q < 4; ++q)
        *(float4*)&x[q*4] = *(const float4*)&XT[tid][bs + q*4];
      #pragma unroll
      for (int tau = 1; tau < 16; ++tau) {
        float a = 0.f, a2 = 0.f;
        #pragma unroll
        for (int m = 0; m < tau; m += 2) {
          a = fmaf(bf2f(Amb[bs+tau][bs+m]), x[m], a);
          if (m + 1 < tau) a2 = fmaf(bf2f(Amb[bs+tau][bs+m+1]), x[m+1], a2);
        }
        x[tau] -= (a + a2);
      }
      #pragma unroll
      for (int q = 0; q < 4; ++q)
        *(float4*)&XT[tid][bs + q*4] = *(const float4*)&x[q*4];
    }
    __syncthreads();
  }

  // ---- write U, W as bf16 ([t][j] layout): float4 LDS reads + coalesced row writes ----
  {
    const int j = tid & 63;
    const int tq4 = tid >> 6;            // 0..3
    #pragma unroll
    for (int i4 = 0; i4 < 4; ++i4) {
      const int t4 = tq4 * 4 + i4;       // 0..15
      float4 uu = *(const float4*)&XT[j][t4*4];
      float4 ww = *(const float4*)&XT[64 + j][t4*4];
      const float ua[4] = {uu.x, uu.y, uu.z, uu.w};
      const float wa[4] = {ww.x, ww.y, ww.z, ww.w};
      #pragma unroll
      for (int r = 0; r < 4; ++r) {
        Ubf[(size_t)bhc*4096 + (size_t)(t4*4 + r)*64 + j] = f2bf(ua[r]);
        Wbf[(size_t)bhc*4096 + (size_t)(t4*4 + r)*64 + j] = f2bf(wa[r]);
      }
    }
  }

  // ---- fused p1b: transpose K into Amb space; scs into bet ----
  u16* KTb = (u16*)&Amb[0][0];           // [64][72] u16, Amb dead after solve
  if (tid < 64) bet[tid] = __expf(gc[63] - gc[tid]);
  __syncthreads();
  for (int e4 = tid; e4 < 1024; e4 += 256) {
    int t = e4 >> 4, a4 = (e4 & 15) * 4;
    u16 k0 = Kbf[t][a4+0], k1 = Kbf[t][a4+1], k2 = Kbf[t][a4+2], k3 = Kbf[t][a4+3];
    KTb[(a4+0)*72 + t] = k0;
    KTb[(a4+1)*72 + t] = k1;
    KTb[(a4+2)*72 + t] = k2;
    KTb[(a4+3)*72 + t] = k3;
  }
  __syncthreads();

  bf16x8 afK[2];
  #pragma unroll
  for (int ks = 0; ks < 2; ++ks)
    afK[ks] = *(const bf16x8*)&KTb[(16*wave + lr)*72 + ks*32 + lkq*8];
  const float bC = __expf(gc[63]);
  const size_t ob = (size_t)bhc * 4096;
  #pragma unroll
  for (int j = 0; j < 4; ++j) {
    f32x4 aM = f32x4{0.f,0.f,0.f,0.f}, aN = f32x4{0.f,0.f,0.f,0.f};
    __builtin_amdgcn_s_setprio(1);
    #pragma unroll
    for (int ks = 0; ks < 2; ++ks) {
      const int m0 = ks*32 + lkq*8;
      float4 sc0 = *(const float4*)&bet[m0];
      float4 sc1 = *(const float4*)&bet[m0 + 4];
      float4 w0 = *(const float4*)&XT[64 + 16*j + lr][m0];
      float4 w1 = *(const float4*)&XT[64 + 16*j + lr][m0 + 4];
      float4 u0 = *(const float4*)&XT[16*j + lr][m0];
      float4 u1 = *(const float4*)&XT[16*j + lr][m0 + 4];
      w0.x*=sc0.x; w0.y*=sc0.y; w0.z*=sc0.z; w0.w*=sc0.w;
      w1.x*=sc1.x; w1.y*=sc1.y; w1.z*=sc1.z; w1.w*=sc1.w;
      u0.x*=sc0.x; u0.y*=sc0.y; u0.z*=sc0.z; u0.w*=sc0.w;
      u1.x*=sc1.x; u1.y*=sc1.y; u1.z*=sc1.z; u1.w*=sc1.w;
      aM = __builtin_amdgcn_mfma_f32_16x16x32_bf16(afK[ks], pack8(w0, w1), aM, 0, 0, 0);
      aN = __builtin_amdgcn_mfma_f32_16x16x32_bf16(afK[ks], pack8(u0, u1), aN, 0, 0, 0);
    }
    __builtin_amdgcn_s_setprio(0);
    const int cc = 16*j + lr;
    #pragma unroll
    for (int r = 0; r < 4; ++r) {
      const int a = 16*wave + lkq*4 + r;
      Mbuf[ob + (size_t)a*64 + cc] = (a == cc ? bC : 0.f) - aM[r];
      Nbuf[ob + (size_t)a*64 + cc] = aN[r];
    }
  }
}

// ---------------- pscanA: in-place group-of-4 prefix composition ----------------
__global__ __launch_bounds__(256) void pscanA(float* __restrict__ Mbuf,
    float* __restrict__ Nbuf)
{
  __shared__ float OM[2][64][68];
  __shared__ float ON[2][64][68];
  __shared__ float NM[2][64][68];
  const int blk = blockIdx.x;
  const int bh = blk >> 3, g = blk & 7;
  const size_t s0 = ((size_t)bh * 32 + g * 4) * 4096;
  const int tid = threadIdx.x;
  const int p0 = (tid >> 4) * 4;
  const int q0 = (tid & 15) * 4;
  for (int e4 = tid; e4 < 1024; e4 += 256) {
    int r = e4 >> 4, c4 = (e4 & 15) * 4;
    *(float4*)&OM[0][r][c4] = *(const float4*)&Mbuf[s0 + (size_t)r*64 + c4];
    *(float4*)&ON[0][r][c4] = *(const float4*)&Nbuf[s0 + (size_t)r*64 + c4];
    *(float4*)&NM[0][r][c4] = *(const float4*)&Mbuf[s0 + 4096 + (size_t)r*64 + c4];
  }
  __syncthreads();
  for (int s = 0; s < 3; ++s) {
    const int cur = s & 1, nxt = cur ^ 1;
    const size_t wslot = s0 + (size_t)(s + 1) * 4096;
    if (s < 2) {
      for (int e4 = tid; e4 < 1024; e4 += 256) {
        int r = e4 >> 4, c4 = (e4 & 15) * 4;
        *(float4*)&NM[nxt][r][c4] = *(const float4*)&Mbuf[wslot + 4096 + (size_t)r*64 + c4];
      }
    }
    float aM[4][4], aN[4][4];
    #pragma unroll
    for (int r = 0; r < 4; ++r) {
      float4 nv = *(const float4*)&Nbuf[wslot + (size_t)(p0+r)*64 + q0];
      aM[r][0]=0.f; aM[r][1]=0.f; aM[r][2]=0.f; aM[r][3]=0.f;
      aN[r][0]=nv.x; aN[r][1]=nv.y; aN[r][2]=nv.z; aN[r][3]=nv.w;
    }
    for (int m4 = 0; m4 < 64; m4 += 4) {
      float xv[4][4];
      #pragma unroll
      for (int r = 0; r < 4; ++r) {
        float4 v = *(const float4*)&NM[cur][p0+r][m4];
        xv[r][0]=v.x; xv[r][1]=v.y; xv[r][2]=v.z; xv[r][3]=v.w;
      }
      #pragma unroll
      for (int mm = 0; mm < 4; ++mm) {
        float4 ym = *(const float4*)&OM[cur][m4+mm][q0];
        float4 yn = *(const float4*)&ON[cur][m4+mm][q0];
        #pragma unroll
        for (int r = 0; r < 4; ++r) {
          aM[r][0] = fmaf(xv[r][mm], ym.x, aM[r][0]);
          aM[r][1] = fmaf(xv[r][mm], ym.y, aM[r][1]);
          aM[r][2] = fmaf(xv[r][mm], ym.z, aM[r][2]);
          aM[r][3] = fmaf(xv[r][mm], ym.w, aM[r][3]);
          aN[r][0] = fmaf(xv[r][mm], yn.x, aN[r][0]);
          aN[r][1] = fmaf(xv[r][mm], yn.y, aN[r][1]);
          aN[r][2] = fmaf(xv[r][mm], yn.z, aN[r][2]);
          aN[r][3] = fmaf(xv[r][mm], yn.w, aN[r][3]);
        }
      }
    }
    #pragma unroll
    for (int r = 0; r < 4; ++r) {
      float4 vm = {aM[r][0], aM[r][1], aM[r][2], aM[r][3]};
      float4 vn = {aN[r][0], aN[r][1], aN[r][2], aN[r][3]};
      *(float4*)&Mbuf[wslot + (size_t)(p0+r)*64 + q0] = vm;
      *(float4*)&Nbuf[wslot + (size_t)(p0+r)*64 + q0] = vn;
      *(float4*)&OM[nxt][p0+r][q0] = vm;
      *(float4*)&ON[nxt][p0+r][q0] = vn;
    }
    __syncthreads();
  }
}

// ---------------- pscanB: serial carry over 8 group totals (ST-form) ----------------
__global__ __launch_bounds__(256) void pscanB(const float* __restrict__ Mbuf,
    const float* __restrict__ Nbuf, float* __restrict__ S0b)
{
  __shared__ float ST[2][64][68];
  __shared__ float MT[64][68];
  const int bh = blockIdx.x;
  const size_t base = (size_t)bh * 32 * 4096;
  const int tid = threadIdx.x;
  const int j0 = (tid >> 4) * 4, a0 = tid & 15;
  for (int e4 = tid; e4 < 1024; e4 += 256) {
    int r = e4 >> 4, c4 = (e4 & 15) * 4;
    *(float4*)&ST[0][r][c4] = float4{0.f, 0.f, 0.f, 0.f};
    *(float4*)&S0b[base + (size_t)r*64 + c4] = float4{0.f, 0.f, 0.f, 0.f};
  }
  for (int g = 0; g < 7; ++g) {
    const int cur = g & 1, nxt = cur ^ 1;
    const size_t tslot = base + (size_t)(4*g + 3) * 4096;
    for (int e4 = tid; e4 < 1024; e4 += 256) {
      int r = e4 >> 4, c4 = (e4 & 15) * 4;
      *(float4*)&MT[r][c4] = *(const float4*)&Mbuf[tslot + (size_t)r*64 + c4];
    }
    float acc[4][4];
    #pragma unroll
    for (int r = 0; r < 4; ++r)
      #pragma unroll
      for (int s = 0; s < 4; ++s)
        acc[r][s] = Nbuf[tslot + (size_t)(a0 + 16*s)*64 + j0 + r];
    __syncthreads();
    for (int k4 = 0; k4 < 64; k4 += 4) {
      float4 xr[4];
      #pragma unroll
      for (int r = 0; r < 4; ++r) xr[r] = *(const float4*)&ST[cur][j0+r][k4];
      #pragma unroll
      for (int s = 0; s < 4; ++s) {
        float4 yv = *(const float4*)&MT[a0 + 16*s][k4];
        #pragma unroll
        for (int r = 0; r < 4; ++r) acc[r][s] = dot4(xr[r], yv, acc[r][s]);
      }
    }
    const size_t oslot = base + (size_t)(4*(g+1)) * 4096;
    #pragma unroll
    for (int r = 0; r < 4; ++r)
      #pragma unroll
      for (int s = 0; s < 4; ++s) {
        ST[nxt][j0+r][a0 + 16*s] = acc[r][s];
        S0b[oslot + (size_t)(j0+r)*64 + a0 + 16*s] = acc[r][s];
      }
    __syncthreads();
  }
}

// ---------------- P3 (MFMA): q-conv+norm inline; fused pscanC (prefix-apply);
//                 delta + outputs + fused ogate ----------------
__global__ __launch_bounds__(256) void p3_out(
    const u16* __restrict__ Qp, const u16* __restrict__ Kcb,
    const float* __restrict__ cqw, const float* __restrict__ qnw,
    const float* __restrict__ Gcum, const float* __restrict__ S0b,
    const float* __restrict__ Mbuf, const float* __restrict__ Nbuf,
    const u16* __restrict__ Ubf, const u16* __restrict__ Wbfg,
    const u16* __restrict__ GV, const float* __restrict__ onw,
    u16* __restrict__ OG)
{
  __shared__ u16 Qbf[64][72];
  __shared__ u16 Kbf[64][72];
  __shared__ u16 S0T[64][72];
  __shared__ u16 Wbf[64][72];
  __shared__ u16 Pbf[64][72];
  __shared__ u16 DsT[64][72];
  __shared__ float gcs[64];
  __shared__ float onws[64];
  const int bhc = blockIdx.x;
  const int bh = bhc >> 5, c = bhc & 31;
  const int b = bh >> 4, h = bh & 15;
  const int tid = threadIdx.x;
  const int lane = tid & 63, wave = tid >> 6;
  const int lr = lane & 15, lkq = lane >> 4;
  const size_t rowbase = ((size_t)b*T_ + c*64)*H_ + h;
  const int c4 = (tid & 15) * 4;
  const int hh64 = h * 64;
  const int ii = c & 3;
  if (tid < 64) { gcs[tid] = Gcum[(size_t)bhc*64 + tid]; onws[tid] = onw[tid]; }

  {
    float4 wq[4];
    float nwv[4];
    #pragma unroll
    for (int cc = 0; cc < 4; ++cc) {
      wq[cc] = *(const float4*)(cqw + (hh64 + c4 + cc) * 4);
      nwv[cc] = qnw[c4 + cc];
    }
    #pragma unroll
    for (int k = 0; k < 4; ++k) {
      const int t = (tid >> 4) + k * 16;
      const int gt = c * 64 + t;
      const u16* src = Qp + (rowbase + (size_t)t * H_) * 64 + c4;
      float4 x3 = ld4bf(src);
      float4 x2 = (gt >= 1) ? ld4bf(src - D_)   : float4{0,0,0,0};
      float4 x1 = (gt >= 2) ? ld4bf(src - 2*D_) : float4{0,0,0,0};
      float4 x0 = (gt >= 3) ? ld4bf(src - 3*D_) : float4{0,0,0,0};
      float4 y = silu4(conv4(x0, x1, x2, x3, wq));
      float ss = fmaf(y.x, y.x, fmaf(y.y, y.y, fmaf(y.z, y.z, y.w * y.w)));
      ss += __shfl_xor(ss, 1); ss += __shfl_xor(ss, 2);
      ss += __shfl_xor(ss, 4); ss += __shfl_xor(ss, 8);
      const float inv1 = rsqrtf(ss * (1.f/64.f) + 1e-6f);
      float4 z = {y.x*inv1*nwv[0], y.y*inv1*nwv[1], y.z*inv1*nwv[2], y.w*inv1*nwv[3]};
      float s2 = fmaf(z.x, z.x, fmaf(z.y, z.y, fmaf(z.z, z.z, z.w * z.w)));
      s2 += __shfl_xor(s2, 1); s2 += __shfl_xor(s2, 2);
      s2 += __shfl_xor(s2, 4); s2 += __shfl_xor(s2, 8);
      const float inv2 = rsqrtf(s2 + 1e-6f) * 0.125f;
      u16 tmp[4] = {f2bf(z.x*inv2), f2bf(z.y*inv2), f2bf(z.z*inv2), f2bf(z.w*inv2)};
      *(uint2*)&Qbf[t][c4] = *(uint2*)tmp;
    }
  }
  for (int e4 = tid; e4 < 1024; e4 += 256) {
    int t = e4 >> 4, d4 = (e4 & 15) * 4;
    *(uint2*)&Kbf[t][d4] = *(const uint2*)&Kcb[(size_t)bhc*4096 + (size_t)t*64 + d4];
    *(uint2*)&Wbf[t][d4] = *(const uint2*)&Wbfg[(size_t)bhc*4096 + (size_t)t*64 + d4];
  }
  if (ii == 0) {
    for (int e4 = tid; e4 < 1024; e4 += 256) {
      int t = e4 >> 4, d4 = (e4 & 15) * 4;
      float4 sv = *(const float4*)&S0b[(size_t)bhc*4096 + (size_t)t*64 + d4];
      u16 as[4] = {f2bf(sv.x), f2bf(sv.y), f2bf(sv.z), f2bf(sv.w)};
      *(uint2*)&S0T[t][d4] = *(uint2*)as;
    }
  } else {
    const size_t gslot = ((size_t)bh*NC_ + (c & ~3)) * 4096;
    const size_t pslot = ((size_t)bh*NC_ + c - 1) * 4096;
    for (int e4 = tid; e4 < 1024; e4 += 256) {
      int t = e4 >> 4, d4 = (e4 & 15) * 4;
      float4 sg = *(const float4*)&S0b[gslot + (size_t)t*64 + d4];
      float4 mp = *(const float4*)&Mbuf[pslot + (size_t)t*64 + d4];
      u16 a1[4] = {f2bf(sg.x), f2bf(sg.y), f2bf(sg.z), f2bf(sg.w)};
      u16 a2[4] = {f2bf(mp.x), f2bf(mp.y), f2bf(mp.z), f2bf(mp.w)};
      *(uint2*)&DsT[t][d4] = *(uint2*)a1;   // STg
      *(uint2*)&Pbf[t][d4] = *(uint2*)a2;   // MP
    }
  }
  __syncthreads();

  if (ii != 0) {
    const size_t pslot = ((size_t)bh*NC_ + c - 1) * 4096;
    bf16x8 ag[2];
    #pragma unroll
    for (int ks = 0; ks < 2; ++ks)
      ag[ks] = *(const bf16x8*)&DsT[16*wave + lr][ks*32 + lkq*8];
    #pragma unroll
    for (int ab = 0; ab < 4; ++ab) {
      f32x4 cin;
      {
        float4 nv = *(const float4*)&Nbuf[pslot + (size_t)(16*ab + lr)*64 + 16*wave + lkq*4];
        cin[0] = nv.x; cin[1] = nv.y; cin[2] = nv.z; cin[3] = nv.w;
      }
      __builtin_amdgcn_s_setprio(1);
      #pragma unroll
      for (int ks = 0; ks < 2; ++ks) {
        bf16x8 bm = *(const bf16x8*)&Pbf[16*ab + lr][ks*32 + lkq*8];
        cin = __builtin_amdgcn_mfma_f32_16x16x32_bf16(ag[ks], bm, cin, 0, 0, 0);
      }
      __builtin_amdgcn_s_setprio(0);
      #pragma unroll
      for (int r = 0; r < 4; ++r)
        S0T[16*wave + lkq*4 + r][16*ab + lr] = f2bf(cin[r]);
    }
    __syncthreads();
  }

  const int trow0 = 16*wave + lkq*4;
  bf16x8 aq[2], aw[2];
  #pragma unroll
  for (int ks = 0; ks < 2; ++ks) {
    aq[ks] = *(const bf16x8*)&Qbf[16*wave + lr][ks*32 + lkq*8];
    aw[ks] = *(const bf16x8*)&Wbf[16*wave + lr][ks*32 + lkq*8];
  }
  float gct[4], egt[4];
  #pragma unroll
  for (int r = 0; r < 4; ++r) { gct[r] = gcs[trow0 + r]; egt[r] = __expf(gct[r]); }

  #pragma unroll
  for (int j = 0; j < 4; ++j) {
    f32x4 pa = f32x4{0.f,0.f,0.f,0.f};
    __builtin_amdgcn_s_setprio(1);
    #pragma unroll
    for (int ks = 0; ks < 2; ++ks) {
      bf16x8 bk = *(const bf16x8*)&Kbf[16*j + lr][ks*32 + lkq*8];
      pa = __builtin_amdgcn_mfma_f32_16x16x32_bf16(aq[ks], bk, pa, 0, 0, 0);
    }
    __builtin_amdgcn_s_setprio(0);
    const int s = 16*j + lr;
    const float gs = gcs[s];
    #pragma unroll
    for (int r = 0; r < 4; ++r) {
      const int t = trow0 + r;
      float val = (s <= t) ? __expf(gct[r] - gs) * pa[r] : 0.f;
      Pbf[t][s] = f2bf(val);
    }
  }

  #pragma unroll
  for (int j = 0; j < 4; ++j) {
    f32x4 da = f32x4{0.f,0.f,0.f,0.f};
    __builtin_amdgcn_s_setprio(1);
    #pragma unroll
    for (int ks = 0; ks < 2; ++ks) {
      bf16x8 bs = *(const bf16x8*)&S0T[16*j + lr][ks*32 + lkq*8];
      da = __builtin_amdgcn_mfma_f32_16x16x32_bf16(aw[ks], bs, da, 0, 0, 0);
    }
    __builtin_amdgcn_s_setprio(0);
    const int jj = 16*j + lr;
    #pragma unroll
    for (int r = 0; r < 4; ++r) {
      const int s = trow0 + r;
      float dv = bf2f(Ubf[(size_t)bhc*4096 + (size_t)s*64 + jj]) - da[r];
      DsT[jj][s] = f2bf(dv);
    }
  }

  f32x4 oacc[4];
  #pragma unroll
  for (int j = 0; j < 4; ++j) {
    f32x4 oa = f32x4{0.f,0.f,0.f,0.f};
    __builtin_amdgcn_s_setprio(1);
    #pragma unroll
    for (int ks = 0; ks < 2; ++ks) {
      bf16x8 bs = *(const bf16x8*)&S0T[16*j + lr][ks*32 + lkq*8];
      oa = __builtin_amdgcn_mfma_f32_16x16x32_bf16(aq[ks], bs, oa, 0, 0, 0);
    }
    __builtin_amdgcn_s_setprio(0);
    #pragma unroll
    for (int r = 0; r < 4; ++r) oa[r] *= egt[r];
    oacc[j] = oa;
  }
  __syncthreads();

  bf16x8 ap[2];
  #pragma unroll
  for (int ks = 0; ks < 2; ++ks)
    ap[ks] = *(const bf16x8*)&Pbf[16*wave + lr][ks*32 + lkq*8];
  __builtin_amdgcn_s_setprio(1);
  #pragma unroll
  for (int j = 0; j < 4; ++j) {
    #pragma unroll
    for (int ks = 0; ks < 2; ++ks) {
      bf16x8 bd = *(const bf16x8*)&DsT[16*j + lr][ks*32 + lkq*8];
      oacc[j] = __builtin_amdgcn_mfma_f32_16x16x32_bf16(ap[ks], bd, oacc[j], 0, 0, 0);
    }
  }
  __builtin_amdgcn_s_setprio(0);

  #pragma unroll
  for (int r = 0; r < 4; ++r) {
    float ss = 0.f;
    #pragma unroll
    for (int jq = 0; jq < 4; ++jq) ss = fmaf(oacc[jq][r], oacc[jq][r], ss);
    ss += __shfl_xor(ss, 1); ss += __shfl_xor(ss, 2);
    ss += __shfl_xor(ss, 4); ss += __shfl_xor(ss, 8);
    const float inv = rsqrtf(ss * (1.f/64.f) + 1e-6f);
    const int t = trow0 + r;
    const size_t rowoff = ((size_t)b*T_ + (size_t)c*64 + t) * D_ + h*64;
    #pragma unroll
    for (int jq = 0; jq < 4; ++jq) {
      const int jj = 16*jq + lr;
      float y = oacc[jq][r] * inv * onws[jj];
      float gv = bf2f(GV[rowoff + jj]);
      OG[rowoff + jj] = f2bf(y * gv / (1.f + __expf(-gv)));
    }
  }
}

extern "C" void kernel_launch(void* const* d_in, const int* in_sizes, int n_in,
                              void* d_out, int out_size, void* d_ws, size_t ws_size,
                              hipStream_t stream) {
  const float* h    = (const float*)d_in[0];
  const float* Wq   = (const float*)d_in[1];
  const float* Wk   = (const float*)d_in[2];
  const float* Wv   = (const float*)d_in[3];
  const float* Wa   = (const float*)d_in[4];
  const float* Wb   = (const float*)d_in[5];
  const float* Wg   = (const float*)d_in[6];
  const float* Wo   = (const float*)d_in[7];
  const float* qnw  = (const float*)d_in[8];
  const float* knw  = (const float*)d_in[9];
  const float* onw  = (const float*)d_in[10];
  const float* Alog = (const float*)d_in[11];
  const float* dtb  = (const float*)d_in[12];
  const float* cqw  = (const float*)d_in[13];
  const float* ckw  = (const float*)d_in[14];
  const float* cvw  = (const float*)d_in[15];
  float* out = (float*)d_out;
  float* ws  = (float*)d_ws;

  const size_t NB = (size_t)B_ * T_ * D_;     // 4,194,304
  float* qp   = ws;
  float* kp   = ws + 1*NB;
  float* vp   = ws + 2*NB;
  float* gvp  = ws + 3*NB;
  float* qc   = ws + 4*NB;
  float* kc   = ws + 5*NB;
  float* vc   = ws + 6*NB;
  float* mb   = ws + 7*NB;
  float* wbf  = ws + 8*NB;
  float* gb   = ws + 8*NB + 5*524288;
  float* bb   = gb + (size_t)B_*T_*H_;
  float* Gc   = bb + (size_t)B_*T_*H_;

  u16* h_bf  = (u16*)mb;
  u16* og_bf = (u16*)kp;
  u16* w_bf  = (u16*)wbf;
  u16* wq_bf = w_bf + 0*1048576;
  u16* wk_bf = w_bf + 1*1048576;
  u16* wv_bf = w_bf + 2*1048576;
  u16* wg_bf = w_bf + 3*1048576;
  u16* wo_bf = w_bf + 4*1048576;

  u16*   Qpb  = (u16*)qp;
  u16*   Kpb  = (u16*)kp;
  u16*   Vpb  = (u16*)vp;
  u16*   GVb  = (u16*)gvp;
  u16*   Ubf  = (u16*)qc;
  u16*   Wbfp = (u16*)qc + NB;
  u16*   Kcb  = (u16*)kc;
  float* Nbuf = vc;
  float* S0b  = vp;
  float* Mbuf = mb;

  cvt_all<<<4608, 256, 0, stream>>>(h, Wq, Wk, Wv, Wg, Wo, h_bf, w_bf);

  gemm_bf16_4<<<dim3(16, 16), 512, 0, stream>>>(h_bf, wq_bf, wk_bf, wv_bf, wg_bf,
                                                 Qpb, Kpb, Vpb, GVb);
  smallproj<<<256, 256, 0, stream>>>(h, Wa, Wb, Alog, dtb, gb, bb);

  p1_chunk<<<B_*H_*NC_, 256, 0, stream>>>(Kpb, Vpb, gb, bb, ckw, cvw, knw,
                                          Ubf, Wbfp, Kcb, Gc, Mbuf, Nbuf);
  pscanA<<<B_*H_*8, 256, 0, stream>>>(Mbuf, Nbuf);
  pscanB<<<B_*H_, 256, 0, stream>>>(Mbuf, Nbuf, S0b);
  p3_out<<<B_*H_*NC_, 256, 0, stream>>>(Qpb, Kcb, cqw, qnw, Gc, S0b, Mbuf, Nbuf,
                                        Ubf, Wbfp, GVb, onw, og_bf);

  gemm_bf16_1<<<dim3(32, 8), 256, 0, stream>>>(og_bf, wo_bf, out);
}

// Round 21
// 209.659 us; speedup vs baseline: 1.0064x; 1.0064x over previous
//
#include <hip/hip_runtime.h>
#include <cstdint>
#include <cstddef>

#define B_ 2
#define T_ 2048
#define D_ 1024
#define H_ 16
#define HD_ 64
#define NC_ 32

typedef unsigned short u16;
typedef __attribute__((ext_vector_type(8))) short bf16x8;
typedef __attribute__((ext_vector_type(4))) float f32x4;

__device__ __forceinline__ float dot4(float4 a, float4 b, float acc) {
  return fmaf(a.x, b.x, fmaf(a.y, b.y, fmaf(a.z, b.z, fmaf(a.w, b.w, acc))));
}
__device__ __forceinline__ u16 f2bf(float f) {
  unsigned u = __float_as_uint(f);
  u += 0x7fffu + ((u >> 16) & 1u);
  return (u16)(u >> 16);
}
__device__ __forceinline__ float bf2f(u16 v) {
  return __uint_as_float(((unsigned)v) << 16);
}
__device__ __forceinline__ float4 ld4bf(const u16* p) {
  uint2 v = *(const uint2*)p;
  return float4{__uint_as_float(v.x << 16),
                __uint_as_float(v.x & 0xffff0000u),
                __uint_as_float(v.y << 16),
                __uint_as_float(v.y & 0xffff0000u)};
}
__device__ __forceinline__ bf16x8 pack8(float4 a, float4 b) {
  union { u16 us[8]; bf16x8 v; } p;
  p.us[0] = f2bf(a.x); p.us[1] = f2bf(a.y); p.us[2] = f2bf(a.z); p.us[3] = f2bf(a.w);
  p.us[4] = f2bf(b.x); p.us[5] = f2bf(b.y); p.us[6] = f2bf(b.z); p.us[7] = f2bf(b.w);
  return p.v;
}
__device__ __forceinline__ void glds16(const u16* g, u16* l) {
  __builtin_amdgcn_global_load_lds(
      (const __attribute__((address_space(1))) void*)g,
      (__attribute__((address_space(3))) void*)l, 16, 0, 0);
}
// swizzled LDS layout for 64x64 u16 tiles: two [64][32] halves, 64B rows,
// 16B-chunk XOR (gemm4's measured-0-conflict pattern). c in [0,64).
__device__ __forceinline__ int lof(int r, int c) {
  return ((c >> 5) << 11) + (r << 5) + (((((c >> 3) & 3) ^ ((r >> 1) & 3))) << 3) + (c & 7);
}
// causal conv (K=4) on 4 columns; w[cc] = taps for column cc
__device__ __forceinline__ float4 conv4(float4 x0, float4 x1, float4 x2, float4 x3,
                                        const float4* w) {
  float4 y;
  y.x = fmaf(w[0].x, x0.x, fmaf(w[0].y, x1.x, fmaf(w[0].z, x2.x, w[0].w * x3.x)));
  y.y = fmaf(w[1].x, x0.y, fmaf(w[1].y, x1.y, fmaf(w[1].z, x2.y, w[1].w * x3.y)));
  y.z = fmaf(w[2].x, x0.z, fmaf(w[2].y, x1.z, fmaf(w[2].z, x2.z, w[2].w * x3.z)));
  y.w = fmaf(w[3].x, x0.w, fmaf(w[3].y, x1.w, fmaf(w[3].z, x2.w, w[3].w * x3.w)));
  return y;
}
__device__ __forceinline__ float4 silu4(float4 a) {
  return float4{a.x / (1.f + __expf(-a.x)), a.y / (1.f + __expf(-a.y)),
                a.z / (1.f + __expf(-a.z)), a.w / (1.f + __expf(-a.w))};
}

// ---------------- fp32 -> bf16 conversion (h + 5 weights, one launch) ----------------
__global__ __launch_bounds__(256) void cvt_all(
    const float* __restrict__ h, const float* __restrict__ w0,
    const float* __restrict__ w1, const float* __restrict__ w2,
    const float* __restrict__ w3, const float* __restrict__ w4,
    u16* __restrict__ h_bf, u16* __restrict__ wb)
{
  const int blk = blockIdx.x;
  const float* src;
  u16* dst;
  int lb;
  if (blk < 2048) { src = h; dst = h_bf; lb = blk; }
  else {
    int k = (blk - 2048) >> 9, r = (blk - 2048) & 511;
    src = k == 0 ? w0 : k == 1 ? w1 : k == 2 ? w2 : k == 3 ? w3 : w4;
    dst = wb + (size_t)k * 1048576;
    lb = r;
  }
  int i = (lb * 256 + threadIdx.x) * 8;
  float4 v0 = *(const float4*)(src + i);
  float4 v1 = *(const float4*)(src + i + 4);
  union { u16 us[8]; uint4 u4; } p;
  p.us[0] = f2bf(v0.x); p.us[1] = f2bf(v0.y); p.us[2] = f2bf(v0.z); p.us[3] = f2bf(v0.w);
  p.us[4] = f2bf(v1.x); p.us[5] = f2bf(v1.y); p.us[6] = f2bf(v1.z); p.us[7] = f2bf(v1.w);
  *(uint4*)(dst + i) = p.u4;
}

// ---- 256x256 GEMM (bf16 out): 8 waves x (128x64), BK=64, 4-phase/tile, counted vmcnt ----
__global__ __launch_bounds__(512, 1) void gemm_bf16_4(const u16* __restrict__ A,
    const u16* __restrict__ W0, const u16* __restrict__ W1,
    const u16* __restrict__ W2, const u16* __restrict__ W3,
    u16* __restrict__ C0, u16* __restrict__ C1,
    u16* __restrict__ C2, u16* __restrict__ C3)
{
  __shared__ u16 L[2 * 32768];   // 128 KB
  const int K = 1024, N = 1024, KT = 16;   // BK = 64
  const int sel = blockIdx.y >> 2;
  const u16* Bw = sel == 0 ? W0 : sel == 1 ? W1 : sel == 2 ? W2 : W3;
  u16* C = sel == 0 ? C0 : sel == 1 ? C1 : sel == 2 ? C2 : C3;
  const int row0 = blockIdx.x * 256;
  const int col0 = (blockIdx.y & 3) * 256;
  const int tid = threadIdx.x;
  const int lane = tid & 63, wave = tid >> 6;
  const int wm = wave >> 2, wn = wave & 3;
  const int lr = lane & 15, lkq = lane >> 4;
  const int rr = tid >> 2, cl = tid & 3;
  const int csw = (cl ^ ((rr >> 1) & 3)) * 8;

  f32x4 acc[8][4];
  #pragma unroll
  for (int i = 0; i < 8; ++i)
    #pragma unroll
    for (int j = 0; j < 4; ++j) acc[i][j] = f32x4{0.f, 0.f, 0.f, 0.f};

  auto STAGEU = [&](int buf, int kt, const u16* src, int matOfs, int baseRow, int ks, int rh) {
    glds16(src + (size_t)(baseRow + rh * 128 + rr) * K + kt * 64 + ks * 32 + csw,
           L + buf * 32768 + matOfs + ks * 8192 + rh * 4096 + tid * 8);
  };
  auto rdA = [&](int buf, int ks, int ih, bf16x8* af) {
    #pragma unroll
    for (int i = 0; i < 4; ++i) {
      const int R = wm * 128 + (ih * 4 + i) * 16 + lr;
      af[i] = *(const bf16x8*)&L[buf * 32768 + ks * 8192 + R * 32 + ((lkq ^ ((R >> 1) & 3)) * 8)];
    }
  };
  auto rdB = [&](int buf, int ks, bf16x8* bf) {
    #pragma unroll
    for (int j = 0; j < 4; ++j) {
      const int R = wn * 64 + j * 16 + lr;
      bf[j] = *(const bf16x8*)&L[buf * 32768 + 16384 + ks * 8192 + R * 32 + ((lkq ^ ((R >> 1) & 3)) * 8)];
    }
  };

  STAGEU(0, 0, A, 0, row0, 0, 0);  STAGEU(0, 0, A, 0, row0, 0, 1);
  STAGEU(0, 0, Bw, 16384, col0, 0, 0); STAGEU(0, 0, Bw, 16384, col0, 0, 1);
  STAGEU(0, 0, A, 0, row0, 1, 0);  STAGEU(0, 0, A, 0, row0, 1, 1);
  STAGEU(0, 0, Bw, 16384, col0, 1, 0); STAGEU(0, 0, Bw, 16384, col0, 1, 1);
  asm volatile("s_waitcnt vmcnt(4)" ::: "memory");
  __builtin_amdgcn_s_barrier();
  __builtin_amdgcn_sched_barrier(0);

  for (int kt = 0; kt < KT; ++kt) {
    const int cb = kt & 1, nb = cb ^ 1;
    const bool st = (kt + 1 < KT);
    bf16x8 af[4], bfr[4];
    rdB(cb, 0, bfr);
    rdA(cb, 0, 0, af);
    if (st) { STAGEU(nb, kt + 1, A, 0, row0, 0, 0); STAGEU(nb, kt + 1, A, 0, row0, 0, 1); }
    __builtin_amdgcn_s_barrier();
    asm volatile("s_waitcnt lgkmcnt(0)" ::: "memory");
    __builtin_amdgcn_sched_barrier(0);
    __builtin_amdgcn_s_setprio(1);
    #pragma unroll
    for (int i = 0; i < 4; ++i)
      #pragma unroll
      for (int j = 0; j < 4; ++j)
        acc[i][j] = __builtin_amdgcn_mfma_f32_16x16x32_bf16(af[i], bfr[j], acc[i][j], 0, 0, 0);
    __builtin_amdgcn_s_setprio(0);
    __builtin_amdgcn_sched_barrier(0);
    __builtin_amdgcn_s_barrier();
    rdA(cb, 0, 1, af);
    if (st) { STAGEU(nb, kt + 1, Bw, 16384, col0, 0, 0); STAGEU(nb, kt + 1, Bw, 16384, col0, 0, 1); }
    if (kt == KT - 1) {
      asm volatile("s_waitcnt vmcnt(0)" ::: "memory");
    } else {
      asm volatile("s_waitcnt vmcnt(4)" ::: "memory");
    }
    __builtin_amdgcn_s_barrier();
    asm volatile("s_waitcnt lgkmcnt(0)" ::: "memory");
    __builtin_amdgcn_sched_barrier(0);
    __builtin_amdgcn_s_setprio(1);
    #pragma unroll
    for (int i = 0; i < 4; ++i)
      #pragma unroll
      for (int j = 0; j < 4; ++j)
        acc[4 + i][j] = __builtin_amdgcn_mfma_f32_16x16x32_bf16(af[i], bfr[j], acc[4 + i][j], 0, 0, 0);
    __builtin_amdgcn_s_setprio(0);
    __builtin_amdgcn_sched_barrier(0);
    __builtin_amdgcn_s_barrier();
    rdB(cb, 1, bfr);
    rdA(cb, 1, 0, af);
    if (st) { STAGEU(nb, kt + 1, A, 0, row0, 1, 0); STAGEU(nb, kt + 1, A, 0, row0, 1, 1); }
    __builtin_amdgcn_s_barrier();
    asm volatile("s_waitcnt lgkmcnt(0)" ::: "memory");
    __builtin_amdgcn_sched_barrier(0);
    __builtin_amdgcn_s_setprio(1);
    #pragma unroll
    for (int i = 0; i < 4; ++i)
      #pragma unroll
      for (int j = 0; j < 4; ++j)
        acc[i][j] = __builtin_amdgcn_mfma_f32_16x16x32_bf16(af[i], bfr[j], acc[i][j], 0, 0, 0);
    __builtin_amdgcn_s_setprio(0);
    __builtin_amdgcn_sched_barrier(0);
    __builtin_amdgcn_s_barrier();
    rdA(cb, 1, 1, af);
    if (st) {
      STAGEU(nb, kt + 1, Bw, 16384, col0, 1, 0); STAGEU(nb, kt + 1, Bw, 16384, col0, 1, 1);
      asm volatile("s_waitcnt vmcnt(4)" ::: "memory");
    }
    __builtin_amdgcn_s_barrier();
    asm volatile("s_waitcnt lgkmcnt(0)" ::: "memory");
    __builtin_amdgcn_sched_barrier(0);
    __builtin_amdgcn_s_setprio(1);
    #pragma unroll
    for (int i = 0; i < 4; ++i)
      #pragma unroll
      for (int j = 0; j < 4; ++j)
        acc[4 + i][j] = __builtin_amdgcn_mfma_f32_16x16x32_bf16(af[i], bfr[j], acc[4 + i][j], 0, 0, 0);
    __builtin_amdgcn_s_setprio(0);
    __builtin_amdgcn_sched_barrier(0);
    __builtin_amdgcn_s_barrier();
  }

  const int orow = row0 + wm * 128 + (lane >> 4) * 4;
  const int ocol = col0 + wn * 64 + lr;
  #pragma unroll
  for (int i = 0; i < 8; ++i)
    #pragma unroll
    for (int j = 0; j < 4; ++j)
      #pragma unroll
      for (int r = 0; r < 4; ++r)
        C[(size_t)(orow + i * 16 + r) * N + ocol + j * 16] = f2bf(acc[i][j][r]);
}

// ---------------- 128x128 GEMM core (fp32 output): 4 waves x (64x64), 3-deep pipeline ----------------
__device__ __forceinline__ void gemm_core128(const u16* __restrict__ A,
    const u16* __restrict__ Bw, float* __restrict__ C,
    u16* As, u16* Bs, int row0, int col0, int K, int N)
{
  const int tid = threadIdx.x;
  const int lane = tid & 63, wave = tid >> 6;
  const int wr = (wave >> 1) * 64, wc = (wave & 1) * 64;
  const int lr = lane & 15;
  const int lkp = (((lane >> 4) ^ ((lr >> 1) & 3))) * 8;
  const int rql = (lane >> 2);
  const int cql = (((lane & 3) ^ ((rql >> 1) & 3))) * 8;
  const u16* gA0 = A + (size_t)(row0 + wave * 16 + rql) * K + cql;
  const u16* gA1 = A + (size_t)(row0 + (wave + 4) * 16 + rql) * K + cql;
  const u16* gB0 = Bw + (size_t)(col0 + wave * 16 + rql) * K + cql;
  const u16* gB1 = Bw + (size_t)(col0 + (wave + 4) * 16 + rql) * K + cql;

  f32x4 acc[4][4];
  #pragma unroll
  for (int i = 0; i < 4; ++i)
    #pragma unroll
    for (int j = 0; j < 4; ++j) acc[i][j] = f32x4{0.f, 0.f, 0.f, 0.f};

  auto STAGE = [&](int buf, int kt) {
    u16* ab = As + buf * 4096;
    u16* bb = Bs + buf * 4096;
    glds16(gA0 + kt * 32, ab + wave * 512);
    glds16(gA1 + kt * 32, ab + (wave + 4) * 512);
    glds16(gB0 + kt * 32, bb + wave * 512);
    glds16(gB1 + kt * 32, bb + (wave + 4) * 512);
  };

  const int KT = K >> 5;
  STAGE(0, 0);
  STAGE(1, 1);
  int cur = 0;
  for (int kt = 0; kt < KT; ++kt) {
    if (kt + 2 < KT) {
      STAGE(cur == 0 ? 2 : (cur == 1 ? 0 : 1), kt + 2);
      asm volatile("s_waitcnt vmcnt(8)" ::: "memory");
    } else if (kt + 1 < KT) {
      asm volatile("s_waitcnt vmcnt(4)" ::: "memory");
    } else {
      asm volatile("s_waitcnt vmcnt(0)" ::: "memory");
    }
    __builtin_amdgcn_s_barrier();
    __builtin_amdgcn_sched_barrier(0);
    const u16* Asc = As + cur * 4096;
    const u16* Bsc = Bs + cur * 4096;
    bf16x8 af[4], bf[4];
    #pragma unroll
    for (int i = 0; i < 4; ++i) af[i] = *(const bf16x8*)&Asc[(wr + i * 16 + lr) * 32 + lkp];
    #pragma unroll
    for (int j = 0; j < 4; ++j) bf[j] = *(const bf16x8*)&Bsc[(wc + j * 16 + lr) * 32 + lkp];
    #pragma unroll
    for (int i = 0; i < 4; ++i)
      #pragma unroll
      for (int j = 0; j < 4; ++j)
        acc[i][j] = __builtin_amdgcn_mfma_f32_16x16x32_bf16(af[i], bf[j], acc[i][j], 0, 0, 0);
    __builtin_amdgcn_sched_barrier(0);
    __builtin_amdgcn_s_barrier();
    cur = (cur == 2) ? 0 : cur + 1;
  }
  const int orow = row0 + wr + (lane >> 4) * 4;
  const int ocol = col0 + wc + lr;
  #pragma unroll
  for (int i = 0; i < 4; ++i)
    #pragma unroll
    for (int j = 0; j < 4; ++j)
      #pragma unroll
      for (int r = 0; r < 4; ++r)
        C[(size_t)(orow + i * 16 + r) * N + ocol + j * 16] = acc[i][j][r];
}

__global__ __launch_bounds__(256) void gemm_bf16_1(const u16* __restrict__ A,
    const u16* __restrict__ Bw, float* __restrict__ C)
{
  __shared__ u16 As[3 * 128 * 32];
  __shared__ u16 Bs[3 * 128 * 32];
  gemm_core128(A, Bw, C, As, Bs, blockIdx.x * 128, blockIdx.y * 128, 1024, 1024);
}

// ---------------- smallproj (LDS-tiled fp32): C[4096][32] = h @ [Wa;Wb]^T ----------------
#define SPW 261
__global__ __launch_bounds__(256) void smallproj(const float* __restrict__ Hs,
    const float* __restrict__ Wa, const float* __restrict__ Wb,
    const float* __restrict__ Alog, const float* __restrict__ dtb,
    float* __restrict__ Gout, float* __restrict__ Bout)
{
  __shared__ float hT[16][SPW];
  __shared__ float wT[32][SPW];
  const int row0 = blockIdx.x * 16;
  const int tid = threadIdx.x;
  const int r = tid >> 5;
  const int c = tid & 31;
  float a0 = 0.f, a1 = 0.f;
  for (int kc = 0; kc < 4; ++kc) {
    const int k0 = kc * 256;
    #pragma unroll
    for (int i = 0; i < 4; ++i) {
      int e4 = tid + i * 256;
      int rr = e4 >> 6, k4 = (e4 & 63) * 4;
      *(float4*)&hT[rr][k4] = *(const float4*)&Hs[(size_t)(row0 + rr) * D_ + k0 + k4];
    }
    #pragma unroll
    for (int i = 0; i < 8; ++i) {
      int e4 = tid + i * 256;
      int rr = e4 >> 6, k4 = (e4 & 63) * 4;
      const float* wsrc = (rr < 16) ? (Wa + (size_t)rr * D_) : (Wb + (size_t)(rr - 16) * D_);
      *(float4*)&wT[rr][k4] = *(const float4*)&wsrc[k0 + k4];
    }
    __syncthreads();
    #pragma unroll 8
    for (int k = 0; k < 256; k += 4) {
      float4 wv = *(const float4*)&wT[c][k];
      float4 h0 = *(const float4*)&hT[r][k];
      float4 h1 = *(const float4*)&hT[r + 8][k];
      a0 = dot4(h0, wv, a0);
      a1 = dot4(h1, wv, a1);
    }
    __syncthreads();
  }
  if (c < 16) {
    const float al = -__expf(Alog[c]);
    const float db = dtb[c];
    float x0 = a0 + db, x1 = a1 + db;
    float sp0 = fmaxf(x0, 0.f) + log1pf(__expf(-fabsf(x0)));
    float sp1 = fmaxf(x1, 0.f) + log1pf(__expf(-fabsf(x1)));
    Gout[(size_t)(row0 + r) * H_ + c] = al * sp0;
    Gout[(size_t)(row0 + r + 8) * H_ + c] = al * sp1;
  } else {
    const int hd = c - 16;
    Bout[(size_t)(row0 + r) * H_ + hd] = 1.f / (1.f + __expf(-a0));
    Bout[(size_t)(row0 + r + 8) * H_ + hd] = 1.f / (1.f + __expf(-a1));
  }
}

// ---------------- P1 (fused): conv+SiLU+norm of K, conv+SiLU of V inline (bf16 sources);
//                 A (bf16 LDS, swizzled) = scale(K K^T), blocked MFMA solve -> U,W (bf16),
//                 then M = bC*I - K^T(sc*W), N = K^T(sc*U) ----------------
__global__ __launch_bounds__(256) void p1_chunk(
    const u16* __restrict__ Kp, const u16* __restrict__ Vp,
    const float* __restrict__ Gg, const float* __restrict__ Bb,
    const float* __restrict__ ckw, const float* __restrict__ cvw,
    const float* __restrict__ knw,
    u16* __restrict__ Ubf, u16* __restrict__ Wbf, u16* __restrict__ Kcb,
    float* __restrict__ Gcum, float* __restrict__ Mbuf, float* __restrict__ Nbuf)
{
  __shared__ u16 Kbf[4096];        // swizzled lof() layout
  __shared__ u16 Amb[4096];        // swizzled lof() layout; reused as KTb
  __shared__ float XT[128][68];
  __shared__ float gc[64], bet[64], ekt[64];
  const int bhc = blockIdx.x;
  const int bh = bhc >> 5, c = bhc & 31;
  const int b = bh >> 4, h = bh & 15;
  const int tid = threadIdx.x;
  const int lane = tid & 63, wave = tid >> 6;
  const int lr = lane & 15, lkq = lane >> 4;
  const size_t rowbase = ((size_t)b*T_ + c*64)*H_ + h;
  const int c4 = (tid & 15) * 4;
  const int hh64 = h * 64;

  if (tid < 64) {
    float gv = Gg[rowbase + (size_t)tid*H_];
    #pragma unroll
    for (int off = 1; off < 64; off <<= 1) {
      float up = __shfl_up(gv, off, 64);
      if (tid >= off) gv += up;
    }
    gc[tid] = gv;
    Gcum[(size_t)bhc*64 + tid] = gv;
    float bv = Bb[rowbase + (size_t)tid*H_];
    bet[tid] = bv;
    ekt[tid] = bv * __expf(gv);
  }

  // ---- K staging: conv(K=4)+SiLU+RMSNorm+L2Norm -> bf16 LDS + Kcb global ----
  {
    float4 wk[4];
    float nwv[4];
    #pragma unroll
    for (int cc = 0; cc < 4; ++cc) {
      wk[cc] = *(const float4*)(ckw + (hh64 + c4 + cc) * 4);
      nwv[cc] = knw[c4 + cc];
    }
    #pragma unroll
    for (int k = 0; k < 4; ++k) {
      const int t = (tid >> 4) + k * 16;
      const int gt = c * 64 + t;
      const u16* src = Kp + (rowbase + (size_t)t * H_) * 64 + c4;
      float4 x3 = ld4bf(src);
      float4 x2 = (gt >= 1) ? ld4bf(src - D_)   : float4{0,0,0,0};
      float4 x1 = (gt >= 2) ? ld4bf(src - 2*D_) : float4{0,0,0,0};
      float4 x0 = (gt >= 3) ? ld4bf(src - 3*D_) : float4{0,0,0,0};
      float4 y = silu4(conv4(x0, x1, x2, x3, wk));
      float ss = fmaf(y.x, y.x, fmaf(y.y, y.y, fmaf(y.z, y.z, y.w * y.w)));
      ss += __shfl_xor(ss, 1); ss += __shfl_xor(ss, 2);
      ss += __shfl_xor(ss, 4); ss += __shfl_xor(ss, 8);
      const float inv1 = rsqrtf(ss * (1.f/64.f) + 1e-6f);
      float4 z = {y.x*inv1*nwv[0], y.y*inv1*nwv[1], y.z*inv1*nwv[2], y.w*inv1*nwv[3]};
      float s2 = fmaf(z.x, z.x, fmaf(z.y, z.y, fmaf(z.z, z.z, z.w * z.w)));
      s2 += __shfl_xor(s2, 1); s2 += __shfl_xor(s2, 2);
      s2 += __shfl_xor(s2, 4); s2 += __shfl_xor(s2, 8);
      const float inv2 = rsqrtf(s2 + 1e-6f);
      u16 tmp[4] = {f2bf(z.x*inv2), f2bf(z.y*inv2), f2bf(z.z*inv2), f2bf(z.w*inv2)};
      *(uint2*)&Kbf[lof(t, c4)] = *(uint2*)tmp;
      *(uint2*)&Kcb[(size_t)bhc*4096 + (size_t)t*64 + c4] = *(uint2*)tmp;
    }
  }
  __syncthreads();

  // ---- A-phase: wave w computes t-strip [16w,16w+16) x all s (bf16 store) ----
  {
    bf16x8 afA[2];
    #pragma unroll
    for (int ks = 0; ks < 2; ++ks)
      afA[ks] = *(const bf16x8*)&Kbf[lof(16*wave + lr, ks*32 + lkq*8)];
    __builtin_amdgcn_s_setprio(1);
    #pragma unroll
    for (int j = 0; j < 4; ++j) {
      f32x4 accA = f32x4{0.f, 0.f, 0.f, 0.f};
      #pragma unroll
      for (int ks = 0; ks < 2; ++ks) {
        bf16x8 bfr = *(const bf16x8*)&Kbf[lof(16*j + lr, ks*32 + lkq*8)];
        accA = __builtin_amdgcn_mfma_f32_16x16x32_bf16(afA[ks], bfr, accA, 0, 0, 0);
      }
      const int s = 16*j + lr;
      #pragma unroll
      for (int r = 0; r < 4; ++r) {
        int t = 16*wave + lkq*4 + r;
        Amb[lof(t, s)] = (s < t) ? f2bf(bet[t] * __expf(gc[t] - gc[s]) * accA[r]) : (u16)0;
      }
    }
    __builtin_amdgcn_s_setprio(0);
  }
  // ---- RHS fill: V conv+SiLU, col-per-lane mapping (conflict-free float4 XT writes) ----
  {
    const int ccol = tid & 63;
    const int tq = tid >> 6;             // t range [16tq, 16tq+16)
    const float4 wv = *(const float4*)(cvw + (hh64 + ccol) * 4);
    float xv[19];
    #pragma unroll
    for (int i = 0; i < 19; ++i) {
      const int t = 16*tq - 3 + i;
      const int gt = c * 64 + t;
      xv[i] = (gt >= 0)
            ? bf2f(Vp[(long long)rowbase * 64 + (long long)t * (H_*64) + ccol])
            : 0.f;
    }
    float o1[16], o2[16];
    #pragma unroll
    for (int i = 0; i < 16; ++i) {
      const int t = 16*tq + i;
      float a = fmaf(wv.x, xv[i], fmaf(wv.y, xv[i+1], fmaf(wv.z, xv[i+2], wv.w * xv[i+3])));
      float y = a / (1.f + __expf(-a));
      o1[i] = bet[t] * y;
      o2[i] = ekt[t] * bf2f(Kbf[lof(t, ccol)]);
    }
    #pragma unroll
    for (int q = 0; q < 4; ++q) {
      *(float4*)&XT[ccol][16*tq + q*4]      = *(float4*)&o1[q*4];
      *(float4*)&XT[64 + ccol][16*tq + q*4] = *(float4*)&o2[q*4];
    }
  }
  __syncthreads();

  // ---- blocked forward substitution: 4 stages of 16 rows ----
  for (int st = 0; st < 4; ++st) {
    if (st > 0) {
      const int nks = (st == 3) ? 2 : 1;
      f32x4 accU0 = f32x4{0.f,0.f,0.f,0.f}, accU1 = f32x4{0.f,0.f,0.f,0.f};
      __builtin_amdgcn_s_setprio(1);
      for (int ks = 0; ks < nks; ++ks) {
        const int m0 = ks*32 + lkq*8;
        bf16x8 af;
        if (m0 + 8 <= 16*st) {
          af = *(const bf16x8*)&Amb[lof(16*st + lr, m0)];
        } else {
          af = bf16x8{0,0,0,0,0,0,0,0};
        }
        {
          const int cb = (wave*2 + 0) * 16;
          float4 b0 = *(const float4*)&XT[cb + lr][m0];
          float4 b1 = *(const float4*)&XT[cb + lr][m0 + 4];
          accU0 = __builtin_amdgcn_mfma_f32_16x16x32_bf16(af, pack8(b0, b1), accU0, 0, 0, 0);
        }
        {
          const int cb = (wave*2 + 1) * 16;
          float4 b0 = *(const float4*)&XT[cb + lr][m0];
          float4 b1 = *(const float4*)&XT[cb + lr][m0 + 4];
          accU1 = __builtin_amdgcn_mfma_f32_16x16x32_bf16(af, pack8(b0, b1), accU1, 0, 0, 0);
        }
      }
      __builtin_amdgcn_s_setprio(0);
      #pragma unroll
      for (int r = 0; r < 4; ++r) {
        const int t = 16*st + lkq*4 + r;
        XT[(wave*2+0)*16 + lr][t] -= accU0[r];
        XT[(wave*2+1)*16 + lr][t] -= accU1[r];
      }
      __syncthreads();
    }
    if (tid < 128) {
      const int bs = 16*st;
      float x[16];
      #pragma unroll
      for (int q = 0; q < 4; ++q)
        *(float4*)&x[q*4] = *(const float4*)&XT[tid][bs + q*4];
      #pragma unroll
      for (int tau = 1; tau < 16; ++tau) {
        float a = 0.f, a2 = 0.f;
        #pragma unroll
        for (int m = 0; m < tau; m += 2) {
          a = fmaf(bf2f(Amb[lof(bs + tau, bs + m)]), x[m], a);
          if (m + 1 < tau) a2 = fmaf(bf2f(Amb[lof(bs + tau, bs + m + 1)]), x[m+1], a2);
        }
        x[tau] -= (a + a2);
      }
      #pragma unroll
      for (int q = 0; q < 4; ++q)
        *(float4*)&XT[tid][bs + q*4] = *(const float4*)&x[q*4];
    }
    __syncthreads();
  }

  // ---- write U, W as bf16 ([t][j] layout): float4 LDS reads + coalesced row writes ----
  {
    const int j = tid & 63;
    const int tq4 = tid >> 6;            // 0..3
    #pragma unroll
    for (int i4 = 0; i4 < 4; ++i4) {
      const int t4 = tq4 * 4 + i4;       // 0..15
      float4 uu = *(const float4*)&XT[j][t4*4];
      float4 ww = *(const float4*)&XT[64 + j][t4*4];
      const float ua[4] = {uu.x, uu.y, uu.z, uu.w};
      const float wa[4] = {ww.x, ww.y, ww.z, ww.w};
      #pragma unroll
      for (int r = 0; r < 4; ++r) {
        Ubf[(size_t)bhc*4096 + (size_t)(t4*4 + r)*64 + j] = f2bf(ua[r]);
        Wbf[(size_t)bhc*4096 + (size_t)(t4*4 + r)*64 + j] = f2bf(wa[r]);
      }
    }
  }

  // ---- fused p1b: transpose K into Amb space; scs into bet ----
  u16* KTb = Amb;                       // Amb dead after solve
  if (tid < 64) bet[tid] = __expf(gc[63] - gc[tid]);
  __syncthreads();
  for (int e4 = tid; e4 < 1024; e4 += 256) {
    int t = e4 >> 4, a4 = (e4 & 15) * 4;
    u16 k0 = Kbf[lof(t, a4+0)], k1 = Kbf[lof(t, a4+1)];
    u16 k2 = Kbf[lof(t, a4+2)], k3 = Kbf[lof(t, a4+3)];
    KTb[lof(a4+0, t)] = k0;
    KTb[lof(a4+1, t)] = k1;
    KTb[lof(a4+2, t)] = k2;
    KTb[lof(a4+3, t)] = k3;
  }
  __syncthreads();

  bf16x8 afK[2];
  #pragma unroll
  for (int ks = 0; ks < 2; ++ks)
    afK[ks] = *(const bf16x8*)&KTb[lof(16*wave + lr, ks*32 + lkq*8)];
  const float bC = __expf(gc[63]);
  const size_t ob = (size_t)bhc * 4096;
  #pragma unroll
  for (int j = 0; j < 4; ++j) {
    f32x4 aM = f32x4{0.f,0.f,0.f,0.f}, aN = f32x4{0.f,0.f,0.f,0.f};
    __builtin_amdgcn_s_setprio(1);
    #pragma unroll
    for (int ks = 0; ks < 2; ++ks) {
      const int m0 = ks*32 + lkq*8;
      float4 sc0 = *(const float4*)&bet[m0];
      float4 sc1 = *(const float4*)&bet[m0 + 4];
      float4 w0 = *(const float4*)&XT[64 + 16*j + lr][m0];
      float4 w1 = *(const float4*)&XT[64 + 16*j + lr][m0 + 4];
      float4 u0 = *(const float4*)&XT[16*j + lr][m0];
      float4 u1 = *(const float4*)&XT[16*j + lr][m0 + 4];
      w0.x*=sc0.x; w0.y*=sc0.y; w0.z*=sc0.z; w0.w*=sc0.w;
      w1.x*=sc1.x; w1.y*=sc1.y; w1.z*=sc1.z; w1.w*=sc1.w;
      u0.x*=sc0.x; u0.y*=sc0.y; u0.z*=sc0.z; u0.w*=sc0.w;
      u1.x*=sc1.x; u1.y*=sc1.y; u1.z*=sc1.z; u1.w*=sc1.w;
      aM = __builtin_amdgcn_mfma_f32_16x16x32_bf16(afK[ks], pack8(w0, w1), aM, 0, 0, 0);
      aN = __builtin_amdgcn_mfma_f32_16x16x32_bf16(afK[ks], pack8(u0, u1), aN, 0, 0, 0);
    }
    __builtin_amdgcn_s_setprio(0);
    const int cc = 16*j + lr;
    #pragma unroll
    for (int r = 0; r < 4; ++r) {
      const int a = 16*wave + lkq*4 + r;
      Mbuf[ob + (size_t)a*64 + cc] = (a == cc ? bC : 0.f) - aM[r];
      Nbuf[ob + (size_t)a*64 + cc] = aN[r];
    }
  }
}

// ---------------- pscanA: in-place group-of-4 prefix composition ----------------
__global__ __launch_bounds__(256) void pscanA(float* __restrict__ Mbuf,
    float* __restrict__ Nbuf)
{
  __shared__ float OM[2][64][68];
  __shared__ float ON[2][64][68];
  __shared__ float NM[2][64][68];
  const int blk = blockIdx.x;
  const int bh = blk >> 3, g = blk & 7;
  const size_t s0 = ((size_t)bh * 32 + g * 4) * 4096;
  const int tid = threadIdx.x;
  const int p0 = (tid >> 4) * 4;
  const int q0 = (tid & 15) * 4;
  for (int e4 = tid; e4 < 1024; e4 += 256) {
    int r = e4 >> 4, c4 = (e4 & 15) * 4;
    *(float4*)&OM[0][r][c4] = *(const float4*)&Mbuf[s0 + (size_t)r*64 + c4];
    *(float4*)&ON[0][r][c4] = *(const float4*)&Nbuf[s0 + (size_t)r*64 + c4];
    *(float4*)&NM[0][r][c4] = *(const float4*)&Mbuf[s0 + 4096 + (size_t)r*64 + c4];
  }
  __syncthreads();
  for (int s = 0; s < 3; ++s) {
    const int cur = s & 1, nxt = cur ^ 1;
    const size_t wslot = s0 + (size_t)(s + 1) * 4096;
    if (s < 2) {
      for (int e4 = tid; e4 < 1024; e4 += 256) {
        int r = e4 >> 4, c4 = (e4 & 15) * 4;
        *(float4*)&NM[nxt][r][c4] = *(const float4*)&Mbuf[wslot + 4096 + (size_t)r*64 + c4];
      }
    }
    float aM[4][4], aN[4][4];
    #pragma unroll
    for (int r = 0; r < 4; ++r) {
      float4 nv = *(const float4*)&Nbuf[wslot + (size_t)(p0+r)*64 + q0];
      aM[r][0]=0.f; aM[r][1]=0.f; aM[r][2]=0.f; aM[r][3]=0.f;
      aN[r][0]=nv.x; aN[r][1]=nv.y; aN[r][2]=nv.z; aN[r][3]=nv.w;
    }
    for (int m4 = 0; m4 < 64; m4 += 4) {
      float xv[4][4];
      #pragma unroll
      for (int r = 0; r < 4; ++r) {
        float4 v = *(const float4*)&NM[cur][p0+r][m4];
        xv[r][0]=v.x; xv[r][1]=v.y; xv[r][2]=v.z; xv[r][3]=v.w;
      }
      #pragma unroll
      for (int mm = 0; mm < 4; ++mm) {
        float4 ym = *(const float4*)&OM[cur][m4+mm][q0];
        float4 yn = *(const float4*)&ON[cur][m4+mm][q0];
        #pragma unroll
        for (int r = 0; r < 4; ++r) {
          aM[r][0] = fmaf(xv[r][mm], ym.x, aM[r][0]);
          aM[r][1] = fmaf(xv[r][mm], ym.y, aM[r][1]);
          aM[r][2] = fmaf(xv[r][mm], ym.z, aM[r][2]);
          aM[r][3] = fmaf(xv[r][mm], ym.w, aM[r][3]);
          aN[r][0] = fmaf(xv[r][mm], yn.x, aN[r][0]);
          aN[r][1] = fmaf(xv[r][mm], yn.y, aN[r][1]);
          aN[r][2] = fmaf(xv[r][mm], yn.z, aN[r][2]);
          aN[r][3] = fmaf(xv[r][mm], yn.w, aN[r][3]);
        }
      }
    }
    #pragma unroll
    for (int r = 0; r < 4; ++r) {
      float4 vm = {aM[r][0], aM[r][1], aM[r][2], aM[r][3]};
      float4 vn = {aN[r][0], aN[r][1], aN[r][2], aN[r][3]};
      *(float4*)&Mbuf[wslot + (size_t)(p0+r)*64 + q0] = vm;
      *(float4*)&Nbuf[wslot + (size_t)(p0+r)*64 + q0] = vn;
      *(float4*)&OM[nxt][p0+r][q0] = vm;
      *(float4*)&ON[nxt][p0+r][q0] = vn;
    }
    __syncthreads();
  }
}

// ---------------- pscanB: serial carry over 8 group totals (ST-form) ----------------
__global__ __launch_bounds__(256) void pscanB(const float* __restrict__ Mbuf,
    const float* __restrict__ Nbuf, float* __restrict__ S0b)
{
  __shared__ float ST[2][64][68];
  __shared__ float MT[64][68];
  const int bh = blockIdx.x;
  const size_t base = (size_t)bh * 32 * 4096;
  const int tid = threadIdx.x;
  const int j0 = (tid >> 4) * 4, a0 = tid & 15;
  for (int e4 = tid; e4 < 1024; e4 += 256) {
    int r = e4 >> 4, c4 = (e4 & 15) * 4;
    *(float4*)&ST[0][r][c4] = float4{0.f, 0.f, 0.f, 0.f};
    *(float4*)&S0b[base + (size_t)r*64 + c4] = float4{0.f, 0.f, 0.f, 0.f};
  }
  for (int g = 0; g < 7; ++g) {
    const int cur = g & 1, nxt = cur ^ 1;
    const size_t tslot = base + (size_t)(4*g + 3) * 4096;
    for (int e4 = tid; e4 < 1024; e4 += 256) {
      int r = e4 >> 4, c4 = (e4 & 15) * 4;
      *(float4*)&MT[r][c4] = *(const float4*)&Mbuf[tslot + (size_t)r*64 + c4];
    }
    float acc[4][4];
    #pragma unroll
    for (int r = 0; r < 4; ++r)
      #pragma unroll
      for (int s = 0; s < 4; ++s)
        acc[r][s] = Nbuf[tslot + (size_t)(a0 + 16*s)*64 + j0 + r];
    __syncthreads();
    for (int k4 = 0; k4 < 64; k4 += 4) {
      float4 xr[4];
      #pragma unroll
      for (int r = 0; r < 4; ++r) xr[r] = *(const float4*)&ST[cur][j0+r][k4];
      #pragma unroll
      for (int s = 0; s < 4; ++s) {
        float4 yv = *(const float4*)&MT[a0 + 16*s][k4];
        #pragma unroll
        for (int r = 0; r < 4; ++r) acc[r][s] = dot4(xr[r], yv, acc[r][s]);
      }
    }
    const size_t oslot = base + (size_t)(4*(g+1)) * 4096;
    #pragma unroll
    for (int r = 0; r < 4; ++r)
      #pragma unroll
      for (int s = 0; s < 4; ++s) {
        ST[nxt][j0+r][a0 + 16*s] = acc[r][s];
        S0b[oslot + (size_t)(j0+r)*64 + a0 + 16*s] = acc[r][s];
      }
    __syncthreads();
  }
}

// ---------------- P3 (MFMA): q-conv+norm inline; fused pscanC (prefix-apply);
//                 delta + outputs + fused ogate; all 64x64 tiles in swizzled lof() layout ----------------
__global__ __launch_bounds__(256) void p3_out(
    const u16* __restrict__ Qp, const u16* __restrict__ Kcb,
    const float* __restrict__ cqw, const float* __restrict__ qnw,
    const float* __restrict__ Gcum, const float* __restrict__ S0b,
    const float* __restrict__ Mbuf, const float* __restrict__ Nbuf,
    const u16* __restrict__ Ubf, const u16* __restrict__ Wbfg,
    const u16* __restrict__ GV, const float* __restrict__ onw,
    u16* __restrict__ OG)
{
  __shared__ u16 Qbf[4096];
  __shared__ u16 Kbf[4096];
  __shared__ u16 S0T[4096];
  __shared__ u16 Wbf[4096];
  __shared__ u16 Pbf[4096];
  __shared__ u16 DsT[4096];
  __shared__ float gcs[64];
  __shared__ float onws[64];
  const int bhc = blockIdx.x;
  const int bh = bhc >> 5, c = bhc & 31;
  const int b = bh >> 4, h = bh & 15;
  const int tid = threadIdx.x;
  const int lane = tid & 63, wave = tid >> 6;
  const int lr = lane & 15, lkq = lane >> 4;
  const size_t rowbase = ((size_t)b*T_ + c*64)*H_ + h;
  const int c4 = (tid & 15) * 4;
  const int hh64 = h * 64;
  const int ii = c & 3;
  if (tid < 64) { gcs[tid] = Gcum[(size_t)bhc*64 + tid]; onws[tid] = onw[tid]; }

  {
    float4 wq[4];
    float nwv[4];
    #pragma unroll
    for (int cc = 0; cc < 4; ++cc) {
      wq[cc] = *(const float4*)(cqw + (hh64 + c4 + cc) * 4);
      nwv[cc] = qnw[c4 + cc];
    }
    #pragma unroll
    for (int k = 0; k < 4; ++k) {
      const int t = (tid >> 4) + k * 16;
      const int gt = c * 64 + t;
      const u16* src = Qp + (rowbase + (size_t)t * H_) * 64 + c4;
      float4 x3 = ld4bf(src);
      float4 x2 = (gt >= 1) ? ld4bf(src - D_)   : float4{0,0,0,0};
      float4 x1 = (gt >= 2) ? ld4bf(src - 2*D_) : float4{0,0,0,0};
      float4 x0 = (gt >= 3) ? ld4bf(src - 3*D_) : float4{0,0,0,0};
      float4 y = silu4(conv4(x0, x1, x2, x3, wq));
      float ss = fmaf(y.x, y.x, fmaf(y.y, y.y, fmaf(y.z, y.z, y.w * y.w)));
      ss += __shfl_xor(ss, 1); ss += __shfl_xor(ss, 2);
      ss += __shfl_xor(ss, 4); ss += __shfl_xor(ss, 8);
      const float inv1 = rsqrtf(ss * (1.f/64.f) + 1e-6f);
      float4 z = {y.x*inv1*nwv[0], y.y*inv1*nwv[1], y.z*inv1*nwv[2], y.w*inv1*nwv[3]};
      float s2 = fmaf(z.x, z.x, fmaf(z.y, z.y, fmaf(z.z, z.z, z.w * z.w)));
      s2 += __shfl_xor(s2, 1); s2 += __shfl_xor(s2, 2);
      s2 += __shfl_xor(s2, 4); s2 += __shfl_xor(s2, 8);
      const float inv2 = rsqrtf(s2 + 1e-6f) * 0.125f;
      u16 tmp[4] = {f2bf(z.x*inv2), f2bf(z.y*inv2), f2bf(z.z*inv2), f2bf(z.w*inv2)};
      *(uint2*)&Qbf[lof(t, c4)] = *(uint2*)tmp;
    }
  }
  for (int e4 = tid; e4 < 1024; e4 += 256) {
    int t = e4 >> 4, d4 = (e4 & 15) * 4;
    *(uint2*)&Kbf[lof(t, d4)] = *(const uint2*)&Kcb[(size_t)bhc*4096 + (size_t)t*64 + d4];
    *(uint2*)&Wbf[lof(t, d4)] = *(const uint2*)&Wbfg[(size_t)bhc*4096 + (size_t)t*64 + d4];
  }
  if (ii == 0) {
    for (int e4 = tid; e4 < 1024; e4 += 256) {
      int t = e4 >> 4, d4 = (e4 & 15) * 4;
      float4 sv = *(const float4*)&S0b[(size_t)bhc*4096 + (size_t)t*64 + d4];
      u16 as[4] = {f2bf(sv.x), f2bf(sv.y), f2bf(sv.z), f2bf(sv.w)};
      *(uint2*)&S0T[lof(t, d4)] = *(uint2*)as;
    }
  } else {
    const size_t gslot = ((size_t)bh*NC_ + (c & ~3)) * 4096;
    const size_t pslot = ((size_t)bh*NC_ + c - 1) * 4096;
    for (int e4 = tid; e4 < 1024; e4 += 256) {
      int t = e4 >> 4, d4 = (e4 & 15) * 4;
      float4 sg = *(const float4*)&S0b[gslot + (size_t)t*64 + d4];
      float4 mp = *(const float4*)&Mbuf[pslot + (size_t)t*64 + d4];
      u16 a1[4] = {f2bf(sg.x), f2bf(sg.y), f2bf(sg.z), f2bf(sg.w)};
      u16 a2[4] = {f2bf(mp.x), f2bf(mp.y), f2bf(mp.z), f2bf(mp.w)};
      *(uint2*)&DsT[lof(t, d4)] = *(uint2*)a1;   // STg
      *(uint2*)&Pbf[lof(t, d4)] = *(uint2*)a2;   // MP
    }
  }
  __syncthreads();

  if (ii != 0) {
    const size_t pslot = ((size_t)bh*NC_ + c - 1) * 4096;
    bf16x8 ag[2];
    #pragma unroll
    for (int ks = 0; ks < 2; ++ks)
      ag[ks] = *(const bf16x8*)&DsT[lof(16*wave + lr, ks*32 + lkq*8)];
    #pragma unroll
    for (int ab = 0; ab < 4; ++ab) {
      f32x4 cin;
      {
        float4 nv = *(const float4*)&Nbuf[pslot + (size_t)(16*ab + lr)*64 + 16*wave + lkq*4];
        cin[0] = nv.x; cin[1] = nv.y; cin[2] = nv.z; cin[3] = nv.w;
      }
      __builtin_amdgcn_s_setprio(1);
      #pragma unroll
      for (int ks = 0; ks < 2; ++ks) {
        bf16x8 bm = *(const bf16x8*)&Pbf[lof(16*ab + lr, ks*32 + lkq*8)];
        cin = __builtin_amdgcn_mfma_f32_16x16x32_bf16(ag[ks], bm, cin, 0, 0, 0);
      }
      __builtin_amdgcn_s_setprio(0);
      #pragma unroll
      for (int r = 0; r < 4; ++r)
        S0T[lof(16*wave + lkq*4 + r, 16*ab + lr)] = f2bf(cin[r]);
    }
    __syncthreads();
  }

  const int trow0 = 16*wave + lkq*4;
  bf16x8 aq[2], aw[2];
  #pragma unroll
  for (int ks = 0; ks < 2; ++ks) {
    aq[ks] = *(const bf16x8*)&Qbf[lof(16*wave + lr, ks*32 + lkq*8)];
    aw[ks] = *(const bf16x8*)&Wbf[lof(16*wave + lr, ks*32 + lkq*8)];
  }
  float gct[4], egt[4];
  #pragma unroll
  for (int r = 0; r < 4; ++r) { gct[r] = gcs[trow0 + r]; egt[r] = __expf(gct[r]); }

  #pragma unroll
  for (int j = 0; j < 4; ++j) {
    f32x4 pa = f32x4{0.f,0.f,0.f,0.f};
    __builtin_amdgcn_s_setprio(1);
    #pragma unroll
    for (int ks = 0; ks < 2; ++ks) {
      bf16x8 bk = *(const bf16x8*)&Kbf[lof(16*j + lr, ks*32 + lkq*8)];
      pa = __builtin_amdgcn_mfma_f32_16x16x32_bf16(aq[ks], bk, pa, 0, 0, 0);
    }
    __builtin_amdgcn_s_setprio(0);
    const int s = 16*j + lr;
    const float gs = gcs[s];
    #pragma unroll
    for (int r = 0; r < 4; ++r) {
      const int t = trow0 + r;
      float val = (s <= t) ? __expf(gct[r] - gs) * pa[r] : 0.f;
      Pbf[lof(t, s)] = f2bf(val);
    }
  }

  #pragma unroll
  for (int j = 0; j < 4; ++j) {
    f32x4 da = f32x4{0.f,0.f,0.f,0.f};
    __builtin_amdgcn_s_setprio(1);
    #pragma unroll
    for (int ks = 0; ks < 2; ++ks) {
      bf16x8 bs = *(const bf16x8*)&S0T[lof(16*j + lr, ks*32 + lkq*8)];
      da = __builtin_amdgcn_mfma_f32_16x16x32_bf16(aw[ks], bs, da, 0, 0, 0);
    }
    __builtin_amdgcn_s_setprio(0);
    const int jj = 16*j + lr;
    #pragma unroll
    for (int r = 0; r < 4; ++r) {
      const int s = trow0 + r;
      float dv = bf2f(Ubf[(size_t)bhc*4096 + (size_t)s*64 + jj]) - da[r];
      DsT[lof(jj, s)] = f2bf(dv);
    }
  }

  f32x4 oacc[4];
  #pragma unroll
  for (int j = 0; j < 4; ++j) {
    f32x4 oa = f32x4{0.f,0.f,0.f,0.f};
    __builtin_amdgcn_s_setprio(1);
    #pragma unroll
    for (int ks = 0; ks < 2; ++ks) {
      bf16x8 bs = *(const bf16x8*)&S0T[lof(16*j + lr, ks*32 + lkq*8)];
      oa = __builtin_amdgcn_mfma_f32_16x16x32_bf16(aq[ks], bs, oa, 0, 0, 0);
    }
    __builtin_amdgcn_s_setprio(0);
    #pragma unroll
    for (int r = 0; r < 4; ++r) oa[r] *= egt[r];
    oacc[j] = oa;
  }
  __syncthreads();

  bf16x8 ap[2];
  #pragma unroll
  for (int ks = 0; ks < 2; ++ks)
    ap[ks] = *(const bf16x8*)&Pbf[lof(16*wave + lr, ks*32 + lkq*8)];
  __builtin_amdgcn_s_setprio(1);
  #pragma unroll
  for (int j = 0; j < 4; ++j) {
    #pragma unroll
    for (int ks = 0; ks < 2; ++ks) {
      bf16x8 bd = *(const bf16x8*)&DsT[lof(16*j + lr, ks*32 + lkq*8)];
      oacc[j] = __builtin_amdgcn_mfma_f32_16x16x32_bf16(ap[ks], bd, oacc[j], 0, 0, 0);
    }
  }
  __builtin_amdgcn_s_setprio(0);

  #pragma unroll
  for (int r = 0; r < 4; ++r) {
    float ss = 0.f;
    #pragma unroll
    for (int jq = 0; jq < 4; ++jq) ss = fmaf(oacc[jq][r], oacc[jq][r], ss);
    ss += __shfl_xor(ss, 1); ss += __shfl_xor(ss, 2);
    ss += __shfl_xor(ss, 4); ss += __shfl_xor(ss, 8);
    const float inv = rsqrtf(ss * (1.f/64.f) + 1e-6f);
    const int t = trow0 + r;
    const size_t rowoff = ((size_t)b*T_ + (size_t)c*64 + t) * D_ + h*64;
    #pragma unroll
    for (int jq = 0; jq < 4; ++jq) {
      const int jj = 16*jq + lr;
      float y = oacc[jq][r] * inv * onws[jj];
      float gv = bf2f(GV[rowoff + jj]);
      OG[rowoff + jj] = f2bf(y * gv / (1.f + __expf(-gv)));
    }
  }
}

extern "C" void kernel_launch(void* const* d_in, const int* in_sizes, int n_in,
                              void* d_out, int out_size, void* d_ws, size_t ws_size,
                              hipStream_t stream) {
  const float* h    = (const float*)d_in[0];
  const float* Wq   = (const float*)d_in[1];
  const float* Wk   = (const float*)d_in[2];
  const float* Wv   = (const float*)d_in[3];
  const float* Wa   = (const float*)d_in[4];
  const float* Wb   = (const float*)d_in[5];
  const float* Wg   = (const float*)d_in[6];
  const float* Wo   = (const float*)d_in[7];
  const float* qnw  = (const float*)d_in[8];
  const float* knw  = (const float*)d_in[9];
  const float* onw  = (const float*)d_in[10];
  const float* Alog = (const float*)d_in[11];
  const float* dtb  = (const float*)d_in[12];
  const float* cqw  = (const float*)d_in[13];
  const float* ckw  = (const float*)d_in[14];
  const float* cvw  = (const float*)d_in[15];
  float* out = (float*)d_out;
  float* ws  = (float*)d_ws;

  const size_t NB = (size_t)B_ * T_ * D_;     // 4,194,304
  float* qp   = ws;
  float* kp   = ws + 1*NB;
  float* vp   = ws + 2*NB;
  float* gvp  = ws + 3*NB;
  float* qc   = ws + 4*NB;
  float* kc   = ws + 5*NB;
  float* vc   = ws + 6*NB;
  float* mb   = ws + 7*NB;
  float* wbf  = ws + 8*NB;
  float* gb   = ws + 8*NB + 5*524288;
  float* bb   = gb + (size_t)B_*T_*H_;
  float* Gc   = bb + (size_t)B_*T_*H_;

  u16* h_bf  = (u16*)mb;
  u16* og_bf = (u16*)kp;
  u16* w_bf  = (u16*)wbf;
  u16* wq_bf = w_bf + 0*1048576;
  u16* wk_bf = w_bf + 1*1048576;
  u16* wv_bf = w_bf + 2*1048576;
  u16* wg_bf = w_bf + 3*1048576;
  u16* wo_bf = w_bf + 4*1048576;

  u16*   Qpb  = (u16*)qp;
  u16*   Kpb  = (u16*)kp;
  u16*   Vpb  = (u16*)vp;
  u16*   GVb  = (u16*)gvp;
  u16*   Ubf  = (u16*)qc;
  u16*   Wbfp = (u16*)qc + NB;
  u16*   Kcb  = (u16*)kc;
  float* Nbuf = vc;
  float* S0b  = vp;
  float* Mbuf = mb;

  cvt_all<<<4608, 256, 0, stream>>>(h, Wq, Wk, Wv, Wg, Wo, h_bf, w_bf);

  gemm_bf16_4<<<dim3(16, 16), 512, 0, stream>>>(h_bf, wq_bf, wk_bf, wv_bf, wg_bf,
                                                 Qpb, Kpb, Vpb, GVb);
  smallproj<<<256, 256, 0, stream>>>(h, Wa, Wb, Alog, dtb, gb, bb);

  p1_chunk<<<B_*H_*NC_, 256, 0, stream>>>(Kpb, Vpb, gb, bb, ckw, cvw, knw,
                                          Ubf, Wbfp, Kcb, Gc, Mbuf, Nbuf);
  pscanA<<<B_*H_*8, 256, 0, stream>>>(Mbuf, Nbuf);
  pscanB<<<B_*H_, 256, 0, stream>>>(Mbuf, Nbuf, S0b);
  p3_out<<<B_*H_*NC_, 256, 0, stream>>>(Qpb, Kcb, cqw, qnw, Gc, S0b, Mbuf, Nbuf,
                                        Ubf, Wbfp, GVb, onw, og_bf);

  gemm_bf16_1<<<dim3(32, 8), 256, 0, stream>>>(og_bf, wo_bf, out);
}